// Round 5
// baseline (1048.490 us; speedup 1.0000x reference)
//
#include <hip/hip_runtime.h>
#include <hip/hip_fp16.h>
#include <cstdint>
#include <cstddef>

#define IN_DIM 128
#define HID    128
#define NG     20
#define T      4096        // edges per binsort1 block
#define MAXB   400         // max coarse bins (N <= 102400)

typedef _Float16 half8 __attribute__((ext_vector_type(8)));
typedef _Float16 half4 __attribute__((ext_vector_type(4)));
typedef float    f32x4 __attribute__((ext_vector_type(4)));

__global__ void zero_ints(int* __restrict__ a, int n) {
  int i = blockIdx.x * blockDim.x + threadIdx.x;
  if (i < n) a[i] = 0;
}

// ============ level 1: block-local sort into coarse bins (256 nodes/bin) ============
__global__ __launch_bounds__(256) void binsort1(const int* __restrict__ src,
    const int* __restrict__ dst, int* __restrict__ tmp, int* __restrict__ bofs,
    int* __restrict__ bintot, int NBC, int E) {
  __shared__ int lhist[MAXB];
  __shared__ int lscan[512];
  __shared__ int lcur[MAXB];
  __shared__ int sbuf[T];
  int tid = threadIdx.x;
  int tile0 = blockIdx.x * T;
  int m = E - tile0; if (m > T) m = T;

  for (int i = tid; i < NBC; i += 256) lhist[i] = 0;
  __syncthreads();

  int dreg[16];
#pragma unroll
  for (int j = 0; j < 16; ++j) {
    int idx = j * 256 + tid;
    dreg[j] = -1;
    if (idx < m) {
      int d = dst[tile0 + idx];
      dreg[j] = d;
      atomicAdd(&lhist[d >> 8], 1);
    }
  }
  __syncthreads();

  int v0 = (tid < NBC) ? lhist[tid] : 0;
  int v1 = (256 + tid < NBC) ? lhist[256 + tid] : 0;
  lscan[tid] = v0; lscan[256 + tid] = v1;
  __syncthreads();
  for (int o = 1; o < 512; o <<= 1) {
    int a0 = (tid >= o) ? lscan[tid - o] : 0;
    int a1 = (256 + tid >= o) ? lscan[256 + tid - o] : 0;
    __syncthreads();
    lscan[tid] += a0; lscan[256 + tid] += a1;
    __syncthreads();
  }
  if (tid < NBC)       lcur[tid]       = lscan[tid] - v0;
  if (256 + tid < NBC) lcur[256 + tid] = lscan[256 + tid] - v1;
  __syncthreads();

  int ST = NBC + 1;
  for (int i = tid; i < NBC; i += 256) bofs[(size_t)blockIdx.x * ST + i] = lcur[i];
  if (tid == 0) bofs[(size_t)blockIdx.x * ST + NBC] = m;
  for (int i = tid; i < NBC; i += 256)
    if (lhist[i]) atomicAdd(&bintot[i], lhist[i]);
  __syncthreads();

#pragma unroll
  for (int j = 0; j < 16; ++j) {
    int idx = j * 256 + tid;
    if (idx < m) {
      int d = dreg[j];
      int s = src[tile0 + idx];
      int slot = atomicAdd(&lcur[d >> 8], 1);
      sbuf[slot] = ((d & 255) << 17) | s;
    }
  }
  __syncthreads();

  int nv = m >> 2;
  int4* out4 = (int4*)(tmp + tile0);
  const int4* sb4 = (const int4*)sbuf;
  for (int i = tid; i < nv; i += 256) out4[i] = sb4[i];
  for (int i = (nv << 2) + tid; i < m; i += 256) tmp[tile0 + i] = sbuf[i];
}

// ============ scan bin totals -> bin bases (1 block) ============
__global__ __launch_bounds__(512) void binscan(const int* __restrict__ bintot,
                                               int* __restrict__ binbase, int NBC) {
  __shared__ int s[512];
  int tid = threadIdx.x;
  int v = (tid < NBC) ? bintot[tid] : 0;
  s[tid] = v;
  __syncthreads();
  for (int o = 1; o < 512; o <<= 1) {
    int t = (tid >= o) ? s[tid - o] : 0;
    __syncthreads();
    s[tid] += t;
    __syncthreads();
  }
  if (tid < NBC) binbase[tid] = s[tid] - v;
}

// ============ level 2: one block per coarse bin -> final CSR + node meta ============
__global__ __launch_bounds__(512) void binsort2(const int* __restrict__ tmp,
    const int* __restrict__ bofs, const int* __restrict__ binbase,
    int* __restrict__ csrc, int* __restrict__ cnt, float* __restrict__ dis,
    int* __restrict__ offs, int NBC, int nblk, int N) {
  __shared__ int lcnt[256];
  __shared__ int lsc[256];
  __shared__ int lcur2[256];
  int b = blockIdx.x;
  int tid = threadIdx.x;
  if (tid < 256) lcnt[tid] = 0;
  __syncthreads();
  int ST = NBC + 1;
  for (int r = tid; r < nblk; r += 512) {
    int s = bofs[(size_t)r * ST + b];
    int e2 = bofs[(size_t)r * ST + b + 1];
    int base = r * T;
    for (int k = s; k < e2; ++k)
      atomicAdd(&lcnt[tmp[base + k] >> 17], 1);
  }
  __syncthreads();
  if (tid < 256) lsc[tid] = lcnt[tid];
  __syncthreads();
  for (int o = 1; o < 256; o <<= 1) {
    int t = 0;
    if (tid < 256 && tid >= o) t = lsc[tid - o];
    __syncthreads();
    if (tid < 256) lsc[tid] += t;
    __syncthreads();
  }
  int gbase = binbase[b];
  if (tid < 256) {
    int excl = lsc[tid] - lcnt[tid];
    lcur2[tid] = gbase + excl;
    int node = (b << 8) + tid;
    if (node < N) {
      cnt[node] = lcnt[tid];
      dis[node] = rsqrtf((float)lcnt[tid] + 1.0f);
      offs[node] = gbase + excl;
    }
  }
  __syncthreads();
  for (int r = tid; r < nblk; r += 512) {
    int s = bofs[(size_t)r * ST + b];
    int e2 = bofs[(size_t)r * ST + b + 1];
    int base = r * T;
    for (int k = s; k < e2; ++k) {
      int rec = tmp[base + k];
      int pos = atomicAdd(&lcur2[rec >> 17], 1);
      csrc[pos] = rec & 0x1FFFF;
    }
  }
}

// ============ MFMA GEMM, f16 out: C16[M,128] = A[M,128] @ B[128,128] ============
__global__ __launch_bounds__(256) void gemm128_mfma(const float* __restrict__ A,
                                                    const float* __restrict__ B,
                                                    __half* __restrict__ C, int M) {
  __shared__ _Float16 sA[128][136];
  const int tid = threadIdx.x;
  const int m0 = blockIdx.x * 128;

#pragma unroll
  for (int q = 0; q < 16; ++q) {
    int idx = q * 256 + tid;
    int r = idx >> 5;
    int cc = (idx & 31) << 2;
    float4 v = make_float4(0.f, 0.f, 0.f, 0.f);
    if (m0 + r < M) v = *(const float4*)(A + (size_t)(m0 + r) * 128 + cc);
    half4 hv;
    hv[0] = (_Float16)v.x; hv[1] = (_Float16)v.y;
    hv[2] = (_Float16)v.z; hv[3] = (_Float16)v.w;
    *(half4*)(&sA[r][cc]) = hv;
  }
  __syncthreads();

  const int wave = tid >> 6, lane = tid & 63;
  const int nbase = wave << 5;
  const int lrow = lane & 15;
  const int khi  = lane >> 4;

  half8 bf[2][4];
#pragma unroll
  for (int nf = 0; nf < 2; ++nf) {
    const float* wcol = B + (nbase + nf * 16 + lrow);
#pragma unroll
    for (int ks = 0; ks < 4; ++ks) {
      half8 hb;
#pragma unroll
      for (int rr = 0; rr < 8; ++rr)
        hb[rr] = (_Float16)wcol[(size_t)(ks * 32 + khi * 8 + rr) * 128];
      bf[nf][ks] = hb;
    }
  }

  f32x4 acc[8][2];
#pragma unroll
  for (int mf = 0; mf < 8; ++mf)
#pragma unroll
    for (int nf = 0; nf < 2; ++nf) acc[mf][nf] = (f32x4){0.f, 0.f, 0.f, 0.f};

#pragma unroll
  for (int mf = 0; mf < 8; ++mf) {
    const _Float16* ar = &sA[mf * 16 + lrow][khi * 8];
    half8 a0 = *(const half8*)(ar);
    half8 a1 = *(const half8*)(ar + 32);
    half8 a2 = *(const half8*)(ar + 64);
    half8 a3 = *(const half8*)(ar + 96);
    acc[mf][0] = __builtin_amdgcn_mfma_f32_16x16x32_f16(a0, bf[0][0], acc[mf][0], 0, 0, 0);
    acc[mf][1] = __builtin_amdgcn_mfma_f32_16x16x32_f16(a0, bf[1][0], acc[mf][1], 0, 0, 0);
    acc[mf][0] = __builtin_amdgcn_mfma_f32_16x16x32_f16(a1, bf[0][1], acc[mf][0], 0, 0, 0);
    acc[mf][1] = __builtin_amdgcn_mfma_f32_16x16x32_f16(a1, bf[1][1], acc[mf][1], 0, 0, 0);
    acc[mf][0] = __builtin_amdgcn_mfma_f32_16x16x32_f16(a2, bf[0][2], acc[mf][0], 0, 0, 0);
    acc[mf][1] = __builtin_amdgcn_mfma_f32_16x16x32_f16(a2, bf[1][2], acc[mf][1], 0, 0, 0);
    acc[mf][0] = __builtin_amdgcn_mfma_f32_16x16x32_f16(a3, bf[0][3], acc[mf][0], 0, 0, 0);
    acc[mf][1] = __builtin_amdgcn_mfma_f32_16x16x32_f16(a3, bf[1][3], acc[mf][1], 0, 0, 0);
  }

#pragma unroll
  for (int mf = 0; mf < 8; ++mf) {
    int r0 = mf * 16 + khi * 4;
#pragma unroll
    for (int nf = 0; nf < 2; ++nf) {
      int ccol = nbase + nf * 16 + lrow;
#pragma unroll
      for (int reg = 0; reg < 4; ++reg) {
        int r = m0 + r0 + reg;
        if (r < M) C[(size_t)r * 128 + ccol] = __float2half(acc[mf][nf][reg]);
      }
    }
  }
}

// ============ aggregation v5: channel-chunked for per-XCD L2 residency ============
// 8 chunks x 16 channels: active gather set = N*16ch*2B = 3.2 MB < 4 MB per-XCD L2.
// Chunk-major grid -> all XCDs phase through chunks together; gathers hit L2.
// Lane layout: g = lane>>3 edge-group (8 edges/instr), l = lane&7 channel pair.
// Per-edge instruction parity with the proven v4 kernel (gather 1, shfl 0.5, FMA same);
// staged w=0 for lanes >= mc makes the variable-srcLane broadcast self-masking.
// No barriers: waves retire independently (R3 lesson).
#define NCHUNK 8
#define CHW    16
__global__ __launch_bounds__(256) void agg_pass(const __half* __restrict__ h,
    const int* __restrict__ csrc, const int* __restrict__ offs,
    const int* __restrict__ cnt, const float* __restrict__ dis,
    const float* __restrict__ bias, float* __restrict__ out,
    int n, int nodeBlocks) {
  const int chunk = blockIdx.x / nodeBlocks;
  const int nb    = blockIdx.x % nodeBlocks;
  const int wave  = threadIdx.x >> 6;
  const int lane  = threadIdx.x & 63;
  const int g = lane >> 3;            // edge group 0..7
  const int l = lane & 7;             // channel lane 0..7
  const int c = chunk * CHW + l * 2;  // this lane's channel pair

  int i0 = (nb * 4 + wave) * 2;
  if (i0 >= n) return;
  int i1 = i0 + 1;
  bool has1 = i1 < n;

  int st0 = offs[i0]; int m0 = cnt[i0]; float d0 = dis[i0];
  int st1 = 0, m1 = 0; float d1 = 0.f;
  if (has1) { st1 = offs[i1]; m1 = cnt[i1]; d1 = dis[i1]; }

  float ax0 = 0.f, ay0 = 0.f, ax1 = 0.f, ay1 = 0.f;
  int mMax = m0 > m1 ? m0 : m1;

  for (int base = 0; base < mMax; base += 64) {
    int mcA = m0 - base; mcA = mcA < 0 ? 0 : (mcA > 64 ? 64 : mcA);
    int mcB = m1 - base; mcB = mcB < 0 ? 0 : (mcB > 64 ? 64 : mcB);
    int mc = mcA > mcB ? mcA : mcB;

    int sA = 0, sB = 0;
    float wA = 0.f, wB = 0.f;
    if (lane < mcA) sA = csrc[st0 + base + lane];
    if (lane < mcB) sB = csrc[st1 + base + lane];
    if (lane < mcA) wA = dis[sA] * d0;
    if (lane < mcB) wB = dis[sB] * d1;

    for (int j = 0; j < mc; j += 8) {
      int idx = j + g;                       // <= 63 always
      int   ea = __shfl(sA, idx);            // staged 0 / w=0 when idx >= mc
      float ua = __shfl(wA, idx);
      int   eb = __shfl(sB, idx);
      float ub = __shfl(wB, idx);
      float2 ha = __half22float2(*(const __half2*)(h + ((size_t)ea << 7) + c));
      float2 hb = __half22float2(*(const __half2*)(h + ((size_t)eb << 7) + c));
      ax0 = fmaf(ha.x, ua, ax0); ay0 = fmaf(ha.y, ua, ay0);
      ax1 = fmaf(hb.x, ub, ax1); ay1 = fmaf(hb.y, ub, ay1);
    }
  }

  // reduce across the 8 edge-groups (lanes sharing the same channel pair)
#pragma unroll
  for (int off = 8; off < 64; off <<= 1) {
    ax0 += __shfl_xor(ax0, off);
    ay0 += __shfl_xor(ay0, off);
    ax1 += __shfl_xor(ax1, off);
    ay1 += __shfl_xor(ay1, off);
  }

  float2 bv = *(const float2*)(bias + c);
  if (g == 0) {
    float dd = d0 * d0;
    float2 hs = __half22float2(*(const __half2*)(h + ((size_t)i0 << 7) + c));
    float vx = fmaf(hs.x, dd, ax0) + bv.x;
    float vy = fmaf(hs.y, dd, ay0) + bv.y;
    *(float2*)(out + (size_t)i0 * 128 + c) = make_float2(fmaxf(vx, 0.f), fmaxf(vy, 0.f));
  } else if (g == 1 && has1) {
    float dd = d1 * d1;
    float2 hs = __half22float2(*(const __half2*)(h + ((size_t)i1 << 7) + c));
    float vx = fmaf(hs.x, dd, ax1) + bv.x;
    float vy = fmaf(hs.y, dd, ay1) + bv.y;
    *(float2*)(out + (size_t)i1 * 128 + c) = make_float2(fmaxf(vx, 0.f), fmaxf(vy, 0.f));
  }
}

// ============ heads: pack 3x[128,20] weights into [128,64] (cols 60..63 zero) ============
__global__ void pack_heads_w(const float* __restrict__ piW, const float* __restrict__ muW,
                             const float* __restrict__ lsW, float* __restrict__ W64) {
  int i = blockIdx.x * 256 + threadIdx.x;
  if (i >= 128 * 64) return;
  int k = i >> 6, j = i & 63;
  float v = 0.f;
  if (j < 20)      v = piW[k * 20 + j];
  else if (j < 40) v = muW[k * 20 + (j - 20)];
  else if (j < 60) v = lsW[k * 20 + (j - 40)];
  W64[i] = v;
}

// ============ heads GEMM: out60[M,64] = A[M,128] @ W64[128,64] ============
#define KC 64
__global__ __launch_bounds__(256) void gemm_heads(const float* __restrict__ A,
                                                  const float* __restrict__ B,
                                                  float* __restrict__ C, int M) {
  __shared__ float sA[64][KC + 4];
  __shared__ float sB[KC][68];
  int tid = threadIdx.x;
  int m0 = blockIdx.x * 64;
  int tr = tid >> 4;   // 0..15
  int tc = tid & 15;   // 0..15
  float acc[4][4];
#pragma unroll
  for (int i = 0; i < 4; ++i)
#pragma unroll
    for (int j = 0; j < 4; ++j) acc[i][j] = 0.f;

  for (int k0 = 0; k0 < 128; k0 += KC) {
#pragma unroll
    for (int q = 0; q < 4; ++q) {
      int idx = q * 256 + tid;
      int r = idx >> 4;
      int kk = (idx & 15) << 2;
      float4 v = make_float4(0.f, 0.f, 0.f, 0.f);
      if (m0 + r < M) v = *(const float4*)(A + (size_t)(m0 + r) * 128 + k0 + kk);
      *(float4*)(&sA[r][kk]) = v;
    }
#pragma unroll
    for (int q = 0; q < 4; ++q) {
      int idx = q * 256 + tid;
      int kk = idx >> 4;
      int nn = (idx & 15) << 2;
      *(float4*)(&sB[kk][nn]) = *(const float4*)(B + (size_t)(k0 + kk) * 64 + nn);
    }
    __syncthreads();
#pragma unroll 4
    for (int k = 0; k < KC; k += 4) {
      float4 a0 = *(const float4*)(&sA[tr][k]);
      float4 a1 = *(const float4*)(&sA[tr + 16][k]);
      float4 a2 = *(const float4*)(&sA[tr + 32][k]);
      float4 a3 = *(const float4*)(&sA[tr + 48][k]);
#pragma unroll
      for (int u = 0; u < 4; ++u) {
        float4 b = *(const float4*)(&sB[k + u][tc * 4]);
        float av[4] = {((const float*)&a0)[u], ((const float*)&a1)[u],
                       ((const float*)&a2)[u], ((const float*)&a3)[u]};
#pragma unroll
        for (int i = 0; i < 4; ++i) {
          acc[i][0] = fmaf(av[i], b.x, acc[i][0]);
          acc[i][1] = fmaf(av[i], b.y, acc[i][1]);
          acc[i][2] = fmaf(av[i], b.z, acc[i][2]);
          acc[i][3] = fmaf(av[i], b.w, acc[i][3]);
        }
      }
    }
    __syncthreads();
  }
#pragma unroll
  for (int i = 0; i < 4; ++i) {
    int r = m0 + tr + 16 * i;
    if (r < M)
      *(float4*)(C + (size_t)r * 64 + tc * 4) =
          make_float4(acc[i][0], acc[i][1], acc[i][2], acc[i][3]);
  }
}

// ============ heads postpass: bias + softmax(20) + scatter ============
__global__ __launch_bounds__(256) void heads_post(const float* __restrict__ out60,
    const float* __restrict__ pib, const float* __restrict__ mub,
    const float* __restrict__ lsb, float* __restrict__ out, int n) {
  int wave = threadIdx.x >> 6, lane = threadIdx.x & 63;
  int node = blockIdx.x * 4 + wave;
  if (node >= n) return;
  float v = 0.f;
  if (lane < 60) {
    v = out60[(size_t)node * 64 + lane];
    v += (lane < 20) ? pib[lane] : (lane < 40) ? mub[lane - 20] : lsb[lane - 40];
  }
  float pv = (lane < 20) ? v : -__builtin_inff();
  float mx = pv;
  for (int o = 16; o > 0; o >>= 1) mx = fmaxf(mx, __shfl_down(mx, o, 32));
  mx = __shfl(mx, 0, 32);
  float ev = (lane < 20) ? expf(v - mx) : 0.f;
  float sm = ev;
  for (int o = 16; o > 0; o >>= 1) sm += __shfl_down(sm, o, 32);
  sm = __shfl(sm, 0, 32);

  size_t base = (size_t)n * NG;
  if (lane < 20)      out[(size_t)node * NG + lane] = ev / sm;
  else if (lane < 40) out[base + (size_t)node * NG + (lane - 20)] = v;
  else if (lane < 60) out[2 * base + (size_t)node * NG + (lane - 40)] = v;
}

extern "C" void kernel_launch(void* const* d_in, const int* in_sizes, int n_in,
                              void* d_out, int out_size, void* d_ws, size_t ws_size,
                              hipStream_t stream) {
  const float* x   = (const float*)d_in[0];
  const int*   ei  = (const int*)d_in[1];
  const float* W1  = (const float*)d_in[2];
  const float* b1  = (const float*)d_in[3];
  const float* W2  = (const float*)d_in[4];
  const float* b2  = (const float*)d_in[5];
  const float* piW = (const float*)d_in[6];
  const float* pib = (const float*)d_in[7];
  const float* muW = (const float*)d_in[8];
  const float* mub = (const float*)d_in[9];
  const float* lsW = (const float*)d_in[10];
  const float* lsb = (const float*)d_in[11];
  float* out = (float*)d_out;

  const int N = in_sizes[0] / IN_DIM;
  const int E = in_sizes[1] / 2;
  const int* src = ei;
  const int* dst = ei + E;

  const int NBC  = (N + 255) >> 8;          // 391 coarse bins
  const int nblk = (E + T - 1) / T;         // 782 level-1 blocks
  const int ST   = NBC + 1;

  // workspace layout (~70 MB)
  char* p = (char*)d_ws;
  char* regionH = p;                        p += (size_t)N * HID * sizeof(__half);
  __half* h16  = (__half*)regionH;
  float* out60 = (float*)regionH;
  char* regionR = p;
  size_t szR = (size_t)N * HID * sizeof(float);
  size_t szT = (size_t)E * sizeof(int);
  p += (szR > szT ? szR : szT);
  int*   tmp    = (int*)regionR;
  float* bufB   = (float*)regionR;
  int*   csrc   = (int*)p;                  p += (size_t)E * sizeof(int);
  int*   bofs   = (int*)p;                  p += (size_t)nblk * ST * sizeof(int);
  int*   bintot = (int*)p;                  p += (size_t)MAXB * sizeof(int);
  int*   binbase= (int*)p;                  p += (size_t)MAXB * sizeof(int);
  int*   cnt    = (int*)p;                  p += (size_t)N * sizeof(int);
  int*   offs   = (int*)p;                  p += (size_t)N * sizeof(int);
  float* dis    = (float*)p;                p += (size_t)N * sizeof(float);
  float* W64    = (float*)p;                p += (size_t)128 * 64 * sizeof(float);

  // ---- CSR build ----
  zero_ints<<<(NBC + 255) / 256, 256, 0, stream>>>(bintot, NBC);
  binsort1<<<nblk, 256, 0, stream>>>(src, dst, tmp, bofs, bintot, NBC, E);
  binscan<<<1, 512, 0, stream>>>(bintot, binbase, NBC);
  binsort2<<<NBC, 512, 0, stream>>>(tmp, bofs, binbase, csrc, cnt, dis, offs,
                                    NBC, nblk, N);
  pack_heads_w<<<(128 * 64 + 255) / 256, 256, 0, stream>>>(piW, muW, lsW, W64);

  const int nodeBlocks = (N + 7) / 8;          // 8 nodes/block (2 per wave)
  const int NBAgg = nodeBlocks * NCHUNK;       // chunk-major grid
  const int NBG  = (N + 127) / 128;            // mfma gemm: 128 rows/block

  // ---- layers ----
  gemm128_mfma<<<NBG, 256, 0, stream>>>(x, W1, h16, N);
  agg_pass<<<NBAgg, 256, 0, stream>>>(h16, csrc, offs, cnt, dis, b1, bufB, N, nodeBlocks);
  gemm128_mfma<<<NBG, 256, 0, stream>>>(bufB, W2, h16, N);
  agg_pass<<<NBAgg, 256, 0, stream>>>(h16, csrc, offs, cnt, dis, b2, bufB, N, nodeBlocks);

  // ---- heads ----
  gemm_heads<<<(N + 63) / 64, 256, 0, stream>>>(bufB, W64, out60, N);
  heads_post<<<(N + 3) / 4, 256, 0, stream>>>(out60, pib, mub, lsb, out, N);
}

// Round 6
// 778.990 us; speedup vs baseline: 1.3460x; 1.3460x over previous
//
#include <hip/hip_runtime.h>
#include <hip/hip_fp16.h>
#include <cstdint>
#include <cstddef>

#define IN_DIM 128
#define HID    128
#define NG     20
#define MAXB   400         // max coarse bins (N <= 102400)

typedef _Float16 half8 __attribute__((ext_vector_type(8)));
typedef _Float16 half4 __attribute__((ext_vector_type(4)));
typedef float    f32x4 __attribute__((ext_vector_type(4)));

__global__ void zero_ints(int* __restrict__ a, int n) {
  int i = blockIdx.x * blockDim.x + threadIdx.x;
  if (i < n) a[i] = 0;
}

// ============ CSR build v2: flat global atomics (replaces 2-level LDS sort) ============
// count: degree histogram via device atomics. 3.2M atomics over 400 KB counters
// (~16 increments per cache line) -- L2-resident, low contention.
__global__ __launch_bounds__(256) void count_deg(const int* __restrict__ dst,
                                                 int* __restrict__ cnt, int E) {
  int e0 = (blockIdx.x * 256 + threadIdx.x) * 4;
#pragma unroll
  for (int j = 0; j < 4; ++j) {
    int e = e0 + j;
    if (e < E) atomicAdd(&cnt[dst[e]], 1);
  }
}

// per-256-node block: local exclusive scan -> offs (partial), block sum -> bsum
__global__ __launch_bounds__(256) void scan_local(const int* __restrict__ cnt,
    int* __restrict__ offs, int* __restrict__ bsum, int N) {
  __shared__ int s[256];
  int tid = threadIdx.x;
  int node = blockIdx.x * 256 + tid;
  int v = (node < N) ? cnt[node] : 0;
  s[tid] = v;
  __syncthreads();
  for (int o = 1; o < 256; o <<= 1) {
    int t = (tid >= o) ? s[tid - o] : 0;
    __syncthreads();
    s[tid] += t;
    __syncthreads();
  }
  if (node < N) offs[node] = s[tid] - v;   // local exclusive
  if (tid == 255) bsum[blockIdx.x] = s[255];
}

// ============ scan bin totals -> bin bases (1 block) ============
__global__ __launch_bounds__(512) void binscan(const int* __restrict__ bintot,
                                               int* __restrict__ binbase, int NBC) {
  __shared__ int s[512];
  int tid = threadIdx.x;
  int v = (tid < NBC) ? bintot[tid] : 0;
  s[tid] = v;
  __syncthreads();
  for (int o = 1; o < 512; o <<= 1) {
    int t = (tid >= o) ? s[tid - o] : 0;
    __syncthreads();
    s[tid] += t;
    __syncthreads();
  }
  if (tid < NBC) binbase[tid] = s[tid] - v;
}

// offs += binbase; gcur = offs; dis = rsqrt(cnt+1)
__global__ __launch_bounds__(256) void finalize_meta(const int* __restrict__ cnt,
    int* __restrict__ offs, int* __restrict__ gcur, float* __restrict__ dis,
    const int* __restrict__ binbase, int N) {
  int node = blockIdx.x * 256 + threadIdx.x;
  if (node >= N) return;
  int o = offs[node] + binbase[node >> 8];
  offs[node] = o;
  gcur[node] = o;
  dis[node] = rsqrtf((float)cnt[node] + 1.0f);
}

// scatter: pos = atomicAdd(gcur[dst]); csrc[pos] = src. Order within a node's
// list is nondeterministic -- harmless (sum is commutative).
__global__ __launch_bounds__(256) void scatter_csr(const int* __restrict__ src,
    const int* __restrict__ dst, int* __restrict__ gcur,
    int* __restrict__ csrc, int E) {
  int e0 = (blockIdx.x * 256 + threadIdx.x) * 4;
#pragma unroll
  for (int j = 0; j < 4; ++j) {
    int e = e0 + j;
    if (e < E) {
      int d = dst[e];
      int s = src[e];
      int pos = atomicAdd(&gcur[d], 1);
      csrc[pos] = s;
    }
  }
}

// ============ MFMA GEMM, f16 out: C16[M,128] = A[M,128] @ B[128,128] ============
__global__ __launch_bounds__(256) void gemm128_mfma(const float* __restrict__ A,
                                                    const float* __restrict__ B,
                                                    __half* __restrict__ C, int M) {
  __shared__ _Float16 sA[128][136];
  const int tid = threadIdx.x;
  const int m0 = blockIdx.x * 128;

#pragma unroll
  for (int q = 0; q < 16; ++q) {
    int idx = q * 256 + tid;
    int r = idx >> 5;
    int cc = (idx & 31) << 2;
    float4 v = make_float4(0.f, 0.f, 0.f, 0.f);
    if (m0 + r < M) v = *(const float4*)(A + (size_t)(m0 + r) * 128 + cc);
    half4 hv;
    hv[0] = (_Float16)v.x; hv[1] = (_Float16)v.y;
    hv[2] = (_Float16)v.z; hv[3] = (_Float16)v.w;
    *(half4*)(&sA[r][cc]) = hv;
  }
  __syncthreads();

  const int wave = tid >> 6, lane = tid & 63;
  const int nbase = wave << 5;
  const int lrow = lane & 15;
  const int khi  = lane >> 4;

  half8 bf[2][4];
#pragma unroll
  for (int nf = 0; nf < 2; ++nf) {
    const float* wcol = B + (nbase + nf * 16 + lrow);
#pragma unroll
    for (int ks = 0; ks < 4; ++ks) {
      half8 hb;
#pragma unroll
      for (int rr = 0; rr < 8; ++rr)
        hb[rr] = (_Float16)wcol[(size_t)(ks * 32 + khi * 8 + rr) * 128];
      bf[nf][ks] = hb;
    }
  }

  f32x4 acc[8][2];
#pragma unroll
  for (int mf = 0; mf < 8; ++mf)
#pragma unroll
    for (int nf = 0; nf < 2; ++nf) acc[mf][nf] = (f32x4){0.f, 0.f, 0.f, 0.f};

#pragma unroll
  for (int mf = 0; mf < 8; ++mf) {
    const _Float16* ar = &sA[mf * 16 + lrow][khi * 8];
    half8 a0 = *(const half8*)(ar);
    half8 a1 = *(const half8*)(ar + 32);
    half8 a2 = *(const half8*)(ar + 64);
    half8 a3 = *(const half8*)(ar + 96);
    acc[mf][0] = __builtin_amdgcn_mfma_f32_16x16x32_f16(a0, bf[0][0], acc[mf][0], 0, 0, 0);
    acc[mf][1] = __builtin_amdgcn_mfma_f32_16x16x32_f16(a0, bf[1][0], acc[mf][1], 0, 0, 0);
    acc[mf][0] = __builtin_amdgcn_mfma_f32_16x16x32_f16(a1, bf[0][1], acc[mf][0], 0, 0, 0);
    acc[mf][1] = __builtin_amdgcn_mfma_f32_16x16x32_f16(a1, bf[1][1], acc[mf][1], 0, 0, 0);
    acc[mf][0] = __builtin_amdgcn_mfma_f32_16x16x32_f16(a2, bf[0][2], acc[mf][0], 0, 0, 0);
    acc[mf][1] = __builtin_amdgcn_mfma_f32_16x16x32_f16(a2, bf[1][2], acc[mf][1], 0, 0, 0);
    acc[mf][0] = __builtin_amdgcn_mfma_f32_16x16x32_f16(a3, bf[0][3], acc[mf][0], 0, 0, 0);
    acc[mf][1] = __builtin_amdgcn_mfma_f32_16x16x32_f16(a3, bf[1][3], acc[mf][1], 0, 0, 0);
  }

#pragma unroll
  for (int mf = 0; mf < 8; ++mf) {
    int r0 = mf * 16 + khi * 4;
#pragma unroll
    for (int nf = 0; nf < 2; ++nf) {
      int ccol = nbase + nf * 16 + lrow;
#pragma unroll
      for (int reg = 0; reg < 4; ++reg) {
        int r = m0 + r0 + reg;
        if (r < M) C[(size_t)r * 128 + ccol] = __float2half(acc[mf][nf][reg]);
      }
    }
  }
}

// ============ aggregation: two nodes per wave, interleaved gather chains ============
// PROVEN STRUCTURE (R4: 115 us @ 3.75 TB/s). Full 256 B row per gather wave is
// traffic-optimal (R5 channel-chunking over-fetched 3.4x). Waves retire
// independently -- no barriers (R3 lesson). Fabric-bound pattern roofline.
__global__ __launch_bounds__(256) void agg_kernel(const __half* __restrict__ h,
    const int* __restrict__ csrc,
    const int* __restrict__ offs, const int* __restrict__ cnt,
    const float* __restrict__ dis, const float* __restrict__ bias,
    float* __restrict__ out, int n) {
  int wave = threadIdx.x >> 6;
  int lane = threadIdx.x & 63;
  int i0 = (blockIdx.x * 4 + wave) * 2;
  if (i0 >= n) return;
  int i1 = i0 + 1;
  bool has1 = i1 < n;
  int c = lane * 2;

  int st0 = offs[i0];
  int m0  = cnt[i0];
  float d0 = dis[i0];
  int st1 = 0, m1 = 0;
  float d1 = 0.f;
  if (has1) { st1 = offs[i1]; m1 = cnt[i1]; d1 = dis[i1]; }

  float ax0 = 0.f, ay0 = 0.f, ax1 = 0.f, ay1 = 0.f;
  int mMax = m0 > m1 ? m0 : m1;

  for (int base = 0; base < mMax; base += 64) {
    int mcA = m0 - base; mcA = mcA < 0 ? 0 : (mcA > 64 ? 64 : mcA);
    int mcB = m1 - base; mcB = mcB < 0 ? 0 : (mcB > 64 ? 64 : mcB);
    int mc = mcA > mcB ? mcA : mcB;

    int sA = 0, sB = 0;
    float wA = 0.f, wB = 0.f;
    if (lane < mcA) sA = csrc[st0 + base + lane];
    if (lane < mcB) sB = csrc[st1 + base + lane];
    if (lane < mcA) wA = dis[sA] * d0;
    if (lane < mcB) wB = dis[sB] * d1;

    int j = 0;
    for (; j + 4 <= mc; j += 4) {
      int   a0 = __shfl(sA, j);
      int   a1 = __shfl(sA, j + 1);
      int   a2 = __shfl(sA, j + 2);
      int   a3 = __shfl(sA, j + 3);
      int   b0 = __shfl(sB, j);
      int   b1 = __shfl(sB, j + 1);
      int   b2 = __shfl(sB, j + 2);
      int   b3 = __shfl(sB, j + 3);
      float u0 = __shfl(wA, j);
      float u1 = __shfl(wA, j + 1);
      float u2 = __shfl(wA, j + 2);
      float u3 = __shfl(wA, j + 3);
      float v0 = __shfl(wB, j);
      float v1 = __shfl(wB, j + 1);
      float v2 = __shfl(wB, j + 2);
      float v3 = __shfl(wB, j + 3);
      float2 hA0 = __half22float2(*(const __half2*)(h + ((size_t)a0 << 7) + c));
      float2 hA1 = __half22float2(*(const __half2*)(h + ((size_t)a1 << 7) + c));
      float2 hA2 = __half22float2(*(const __half2*)(h + ((size_t)a2 << 7) + c));
      float2 hA3 = __half22float2(*(const __half2*)(h + ((size_t)a3 << 7) + c));
      float2 hB0 = __half22float2(*(const __half2*)(h + ((size_t)b0 << 7) + c));
      float2 hB1 = __half22float2(*(const __half2*)(h + ((size_t)b1 << 7) + c));
      float2 hB2 = __half22float2(*(const __half2*)(h + ((size_t)b2 << 7) + c));
      float2 hB3 = __half22float2(*(const __half2*)(h + ((size_t)b3 << 7) + c));
      ax0 = fmaf(hA0.x, u0, ax0); ay0 = fmaf(hA0.y, u0, ay0);
      ax0 = fmaf(hA1.x, u1, ax0); ay0 = fmaf(hA1.y, u1, ay0);
      ax0 = fmaf(hA2.x, u2, ax0); ay0 = fmaf(hA2.y, u2, ay0);
      ax0 = fmaf(hA3.x, u3, ax0); ay0 = fmaf(hA3.y, u3, ay0);
      ax1 = fmaf(hB0.x, v0, ax1); ay1 = fmaf(hB0.y, v0, ay1);
      ax1 = fmaf(hB1.x, v1, ax1); ay1 = fmaf(hB1.y, v1, ay1);
      ax1 = fmaf(hB2.x, v2, ax1); ay1 = fmaf(hB2.y, v2, ay1);
      ax1 = fmaf(hB3.x, v3, ax1); ay1 = fmaf(hB3.y, v3, ay1);
    }
    for (; j < mc; ++j) {
      int   a0 = __shfl(sA, j);
      int   b0 = __shfl(sB, j);
      float u0 = __shfl(wA, j);
      float v0 = __shfl(wB, j);
      float2 hA0 = __half22float2(*(const __half2*)(h + ((size_t)a0 << 7) + c));
      float2 hB0 = __half22float2(*(const __half2*)(h + ((size_t)b0 << 7) + c));
      ax0 = fmaf(hA0.x, u0, ax0); ay0 = fmaf(hA0.y, u0, ay0);
      ax1 = fmaf(hB0.x, v0, ax1); ay1 = fmaf(hB0.y, v0, ay1);
    }
  }

  float2 bv = *(const float2*)(bias + c);
  {
    float dd = d0 * d0;
    float2 hs = __half22float2(*(const __half2*)(h + ((size_t)i0 << 7) + c));
    float vx = fmaf(hs.x, dd, ax0) + bv.x;
    float vy = fmaf(hs.y, dd, ay0) + bv.y;
    *(float2*)(out + (size_t)i0 * 128 + c) = make_float2(fmaxf(vx, 0.f), fmaxf(vy, 0.f));
  }
  if (has1) {
    float dd = d1 * d1;
    float2 hs = __half22float2(*(const __half2*)(h + ((size_t)i1 << 7) + c));
    float vx = fmaf(hs.x, dd, ax1) + bv.x;
    float vy = fmaf(hs.y, dd, ay1) + bv.y;
    *(float2*)(out + (size_t)i1 * 128 + c) = make_float2(fmaxf(vx, 0.f), fmaxf(vy, 0.f));
  }
}

// ============ heads: pack 3x[128,20] weights into [128,64] (cols 60..63 zero) ============
__global__ void pack_heads_w(const float* __restrict__ piW, const float* __restrict__ muW,
                             const float* __restrict__ lsW, float* __restrict__ W64) {
  int i = blockIdx.x * 256 + threadIdx.x;
  if (i >= 128 * 64) return;
  int k = i >> 6, j = i & 63;
  float v = 0.f;
  if (j < 20)      v = piW[k * 20 + j];
  else if (j < 40) v = muW[k * 20 + (j - 20)];
  else if (j < 60) v = lsW[k * 20 + (j - 40)];
  W64[i] = v;
}

// ============ heads GEMM: out60[M,64] = A[M,128] @ W64[128,64] ============
#define KC 64
__global__ __launch_bounds__(256) void gemm_heads(const float* __restrict__ A,
                                                  const float* __restrict__ B,
                                                  float* __restrict__ C, int M) {
  __shared__ float sA[64][KC + 4];
  __shared__ float sB[KC][68];
  int tid = threadIdx.x;
  int m0 = blockIdx.x * 64;
  int tr = tid >> 4;   // 0..15
  int tc = tid & 15;   // 0..15
  float acc[4][4];
#pragma unroll
  for (int i = 0; i < 4; ++i)
#pragma unroll
    for (int j = 0; j < 4; ++j) acc[i][j] = 0.f;

  for (int k0 = 0; k0 < 128; k0 += KC) {
#pragma unroll
    for (int q = 0; q < 4; ++q) {
      int idx = q * 256 + tid;
      int r = idx >> 4;
      int kk = (idx & 15) << 2;
      float4 v = make_float4(0.f, 0.f, 0.f, 0.f);
      if (m0 + r < M) v = *(const float4*)(A + (size_t)(m0 + r) * 128 + k0 + kk);
      *(float4*)(&sA[r][kk]) = v;
    }
#pragma unroll
    for (int q = 0; q < 4; ++q) {
      int idx = q * 256 + tid;
      int kk = idx >> 4;
      int nn = (idx & 15) << 2;
      *(float4*)(&sB[kk][nn]) = *(const float4*)(B + (size_t)(k0 + kk) * 64 + nn);
    }
    __syncthreads();
#pragma unroll 4
    for (int k = 0; k < KC; k += 4) {
      float4 a0 = *(const float4*)(&sA[tr][k]);
      float4 a1 = *(const float4*)(&sA[tr + 16][k]);
      float4 a2 = *(const float4*)(&sA[tr + 32][k]);
      float4 a3 = *(const float4*)(&sA[tr + 48][k]);
#pragma unroll
      for (int u = 0; u < 4; ++u) {
        float4 b = *(const float4*)(&sB[k + u][tc * 4]);
        float av[4] = {((const float*)&a0)[u], ((const float*)&a1)[u],
                       ((const float*)&a2)[u], ((const float*)&a3)[u]};
#pragma unroll
        for (int i = 0; i < 4; ++i) {
          acc[i][0] = fmaf(av[i], b.x, acc[i][0]);
          acc[i][1] = fmaf(av[i], b.y, acc[i][1]);
          acc[i][2] = fmaf(av[i], b.z, acc[i][2]);
          acc[i][3] = fmaf(av[i], b.w, acc[i][3]);
        }
      }
    }
    __syncthreads();
  }
#pragma unroll
  for (int i = 0; i < 4; ++i) {
    int r = m0 + tr + 16 * i;
    if (r < M)
      *(float4*)(C + (size_t)r * 64 + tc * 4) =
          make_float4(acc[i][0], acc[i][1], acc[i][2], acc[i][3]);
  }
}

// ============ heads postpass: bias + softmax(20) + scatter ============
__global__ __launch_bounds__(256) void heads_post(const float* __restrict__ out60,
    const float* __restrict__ pib, const float* __restrict__ mub,
    const float* __restrict__ lsb, float* __restrict__ out, int n) {
  int wave = threadIdx.x >> 6, lane = threadIdx.x & 63;
  int node = blockIdx.x * 4 + wave;
  if (node >= n) return;
  float v = 0.f;
  if (lane < 60) {
    v = out60[(size_t)node * 64 + lane];
    v += (lane < 20) ? pib[lane] : (lane < 40) ? mub[lane - 20] : lsb[lane - 40];
  }
  float pv = (lane < 20) ? v : -__builtin_inff();
  float mx = pv;
  for (int o = 16; o > 0; o >>= 1) mx = fmaxf(mx, __shfl_down(mx, o, 32));
  mx = __shfl(mx, 0, 32);
  float ev = (lane < 20) ? expf(v - mx) : 0.f;
  float sm = ev;
  for (int o = 16; o > 0; o >>= 1) sm += __shfl_down(sm, o, 32);
  sm = __shfl(sm, 0, 32);

  size_t base = (size_t)n * NG;
  if (lane < 20)      out[(size_t)node * NG + lane] = ev / sm;
  else if (lane < 40) out[base + (size_t)node * NG + (lane - 20)] = v;
  else if (lane < 60) out[2 * base + (size_t)node * NG + (lane - 40)] = v;
}

extern "C" void kernel_launch(void* const* d_in, const int* in_sizes, int n_in,
                              void* d_out, int out_size, void* d_ws, size_t ws_size,
                              hipStream_t stream) {
  const float* x   = (const float*)d_in[0];
  const int*   ei  = (const int*)d_in[1];
  const float* W1  = (const float*)d_in[2];
  const float* b1  = (const float*)d_in[3];
  const float* W2  = (const float*)d_in[4];
  const float* b2  = (const float*)d_in[5];
  const float* piW = (const float*)d_in[6];
  const float* pib = (const float*)d_in[7];
  const float* muW = (const float*)d_in[8];
  const float* mub = (const float*)d_in[9];
  const float* lsW = (const float*)d_in[10];
  const float* lsb = (const float*)d_in[11];
  float* out = (float*)d_out;

  const int N = in_sizes[0] / IN_DIM;
  const int E = in_sizes[1] / 2;
  const int* src = ei;
  const int* dst = ei + E;

  const int NBC = (N + 255) >> 8;           // 391 coarse bins

  // workspace layout (~92 MB)
  char* p = (char*)d_ws;
  char* regionH = p;                        p += (size_t)N * HID * sizeof(__half);
  __half* h16  = (__half*)regionH;
  float* out60 = (float*)regionH;
  float* bufB  = (float*)p;                 p += (size_t)N * HID * sizeof(float);
  int*   csrc   = (int*)p;                  p += (size_t)E * sizeof(int);
  int*   bsum   = (int*)p;                  p += (size_t)MAXB * sizeof(int);
  int*   binbase= (int*)p;                  p += (size_t)MAXB * sizeof(int);
  int*   cnt    = (int*)p;                  p += (size_t)N * sizeof(int);
  int*   offs   = (int*)p;                  p += (size_t)N * sizeof(int);
  int*   gcur   = (int*)p;                  p += (size_t)N * sizeof(int);
  float* dis    = (float*)p;                p += (size_t)N * sizeof(float);
  float* W64    = (float*)p;                p += (size_t)128 * 64 * sizeof(float);

  // ---- CSR build (flat atomics) ----
  zero_ints<<<(N + 255) / 256, 256, 0, stream>>>(cnt, N);
  count_deg<<<(E / 4 + 255) / 256, 256, 0, stream>>>(dst, cnt, E);
  scan_local<<<NBC, 256, 0, stream>>>(cnt, offs, bsum, N);
  binscan<<<1, 512, 0, stream>>>(bsum, binbase, NBC);
  finalize_meta<<<(N + 255) / 256, 256, 0, stream>>>(cnt, offs, gcur, dis, binbase, N);
  scatter_csr<<<(E / 4 + 255) / 256, 256, 0, stream>>>(src, dst, gcur, csrc, E);
  pack_heads_w<<<(128 * 64 + 255) / 256, 256, 0, stream>>>(piW, muW, lsW, W64);

  const int NB8 = (N + 7) / 8;       // agg: 2 nodes/wave, 4 waves/block
  const int NBG = (N + 127) / 128;   // mfma gemm: 128 rows/block

  // ---- layers ----
  gemm128_mfma<<<NBG, 256, 0, stream>>>(x, W1, h16, N);
  agg_kernel<<<NB8, 256, 0, stream>>>(h16, csrc, offs, cnt, dis, b1, bufB, N);
  gemm128_mfma<<<NBG, 256, 0, stream>>>(bufB, W2, h16, N);
  agg_kernel<<<NB8, 256, 0, stream>>>(h16, csrc, offs, cnt, dis, b2, bufB, N);

  // ---- heads ----
  gemm_heads<<<(N + 63) / 64, 256, 0, stream>>>(bufB, W64, out60, N);
  heads_post<<<(N + 3) / 4, 256, 0, stream>>>(out60, pib, mub, lsb, out, N);
}

// Round 7
// 550.312 us; speedup vs baseline: 1.9053x; 1.4155x over previous
//
#include <hip/hip_runtime.h>
#include <hip/hip_fp16.h>
#include <cstdint>
#include <cstddef>

#define IN_DIM 128
#define HID    128
#define NG     20
#define T      4096        // edges per binsort1 block
#define MAXB   400         // max coarse bins (N <= 102400)

typedef _Float16 half8 __attribute__((ext_vector_type(8)));
typedef _Float16 half4 __attribute__((ext_vector_type(4)));
typedef float    f32x4 __attribute__((ext_vector_type(4)));

__global__ void zero_ints(int* __restrict__ a, int n) {
  int i = blockIdx.x * blockDim.x + threadIdx.x;
  if (i < n) a[i] = 0;
}

// ============ level 1: block-local sort into coarse bins (256 nodes/bin) ============
// v2: 512 threads (was 256) -- same algorithm, 2x waves to hide LDS-atomic and
// global-load latency. Write phases stay windowed (no write amplification; R6 lesson).
__global__ __launch_bounds__(512) void binsort1(const int* __restrict__ src,
    const int* __restrict__ dst, int* __restrict__ tmp, int* __restrict__ bofs,
    int* __restrict__ bintot, int NBC, int E) {
  __shared__ int lhist[MAXB];
  __shared__ int lscan[512];
  __shared__ int lcur[MAXB];
  __shared__ int sbuf[T];
  int tid = threadIdx.x;
  int tile0 = blockIdx.x * T;
  int m = E - tile0; if (m > T) m = T;

  for (int i = tid; i < NBC; i += 512) lhist[i] = 0;
  __syncthreads();

  int dreg[8];
#pragma unroll
  for (int j = 0; j < 8; ++j) {
    int idx = j * 512 + tid;
    dreg[j] = -1;
    if (idx < m) {
      int d = dst[tile0 + idx];
      dreg[j] = d;
      atomicAdd(&lhist[d >> 8], 1);
    }
  }
  __syncthreads();

  int v = (tid < NBC) ? lhist[tid] : 0;
  lscan[tid] = v;
  __syncthreads();
  for (int o = 1; o < 512; o <<= 1) {
    int t = (tid >= o) ? lscan[tid - o] : 0;
    __syncthreads();
    lscan[tid] += t;
    __syncthreads();
  }
  if (tid < NBC) lcur[tid] = lscan[tid] - v;
  __syncthreads();

  int ST = NBC + 1;
  for (int i = tid; i < NBC; i += 512) bofs[(size_t)blockIdx.x * ST + i] = lcur[i];
  if (tid == 0) bofs[(size_t)blockIdx.x * ST + NBC] = m;
  for (int i = tid; i < NBC; i += 512)
    if (lhist[i]) atomicAdd(&bintot[i], lhist[i]);
  __syncthreads();

#pragma unroll
  for (int j = 0; j < 8; ++j) {
    int idx = j * 512 + tid;
    if (idx < m) {
      int d = dreg[j];
      int s = src[tile0 + idx];
      int slot = atomicAdd(&lcur[d >> 8], 1);
      sbuf[slot] = ((d & 255) << 17) | s;
    }
  }
  __syncthreads();

  int nv = m >> 2;
  int4* out4 = (int4*)(tmp + tile0);
  const int4* sb4 = (const int4*)sbuf;
  for (int i = tid; i < nv; i += 512) out4[i] = sb4[i];
  for (int i = (nv << 2) + tid; i < m; i += 512) tmp[tile0 + i] = sbuf[i];
}

// ============ scan bin totals -> bin bases (1 block) ============
__global__ __launch_bounds__(512) void binscan(const int* __restrict__ bintot,
                                               int* __restrict__ binbase, int NBC) {
  __shared__ int s[512];
  int tid = threadIdx.x;
  int v = (tid < NBC) ? bintot[tid] : 0;
  s[tid] = v;
  __syncthreads();
  for (int o = 1; o < 512; o <<= 1) {
    int t = (tid >= o) ? s[tid - o] : 0;
    __syncthreads();
    s[tid] += t;
    __syncthreads();
  }
  if (tid < NBC) binbase[tid] = s[tid] - v;
}

// ============ level 2: one block per coarse bin -> final CSR + node meta ============
// v2: 1024 threads (was 512) -- every tile-segment (782) gets its own thread in a
// single stride; 2x waves to hide the serial ~10-edge loops and 4B bofs reads.
__global__ __launch_bounds__(1024) void binsort2(const int* __restrict__ tmp,
    const int* __restrict__ bofs, const int* __restrict__ binbase,
    int* __restrict__ csrc, int* __restrict__ cnt, float* __restrict__ dis,
    int* __restrict__ offs, int NBC, int nblk, int N) {
  __shared__ int lcnt[256];
  __shared__ int lsc[256];
  __shared__ int lcur2[256];
  int b = blockIdx.x;
  int tid = threadIdx.x;
  if (tid < 256) lcnt[tid] = 0;
  __syncthreads();
  int ST = NBC + 1;
  for (int r = tid; r < nblk; r += 1024) {
    int s = bofs[(size_t)r * ST + b];
    int e2 = bofs[(size_t)r * ST + b + 1];
    int base = r * T;
    for (int k = s; k < e2; ++k)
      atomicAdd(&lcnt[tmp[base + k] >> 17], 1);
  }
  __syncthreads();
  if (tid < 256) lsc[tid] = lcnt[tid];
  __syncthreads();
  for (int o = 1; o < 256; o <<= 1) {
    int t = 0;
    if (tid < 256 && tid >= o) t = lsc[tid - o];
    __syncthreads();
    if (tid < 256) lsc[tid] += t;
    __syncthreads();
  }
  int gbase = binbase[b];
  if (tid < 256) {
    int excl = lsc[tid] - lcnt[tid];
    lcur2[tid] = gbase + excl;
    int node = (b << 8) + tid;
    if (node < N) {
      cnt[node] = lcnt[tid];
      dis[node] = rsqrtf((float)lcnt[tid] + 1.0f);
      offs[node] = gbase + excl;
    }
  }
  __syncthreads();
  for (int r = tid; r < nblk; r += 1024) {
    int s = bofs[(size_t)r * ST + b];
    int e2 = bofs[(size_t)r * ST + b + 1];
    int base = r * T;
    for (int k = s; k < e2; ++k) {
      int rec = tmp[base + k];
      int pos = atomicAdd(&lcur2[rec >> 17], 1);
      csrc[pos] = rec & 0x1FFFF;
    }
  }
}

// ============ MFMA GEMM, f16 out: C16[M,128] = A[M,128] @ B[128,128] ============
__global__ __launch_bounds__(256) void gemm128_mfma(const float* __restrict__ A,
                                                    const float* __restrict__ B,
                                                    __half* __restrict__ C, int M) {
  __shared__ _Float16 sA[128][136];
  const int tid = threadIdx.x;
  const int m0 = blockIdx.x * 128;

#pragma unroll
  for (int q = 0; q < 16; ++q) {
    int idx = q * 256 + tid;
    int r = idx >> 5;
    int cc = (idx & 31) << 2;
    float4 v = make_float4(0.f, 0.f, 0.f, 0.f);
    if (m0 + r < M) v = *(const float4*)(A + (size_t)(m0 + r) * 128 + cc);
    half4 hv;
    hv[0] = (_Float16)v.x; hv[1] = (_Float16)v.y;
    hv[2] = (_Float16)v.z; hv[3] = (_Float16)v.w;
    *(half4*)(&sA[r][cc]) = hv;
  }
  __syncthreads();

  const int wave = tid >> 6, lane = tid & 63;
  const int nbase = wave << 5;
  const int lrow = lane & 15;
  const int khi  = lane >> 4;

  half8 bf[2][4];
#pragma unroll
  for (int nf = 0; nf < 2; ++nf) {
    const float* wcol = B + (nbase + nf * 16 + lrow);
#pragma unroll
    for (int ks = 0; ks < 4; ++ks) {
      half8 hb;
#pragma unroll
      for (int rr = 0; rr < 8; ++rr)
        hb[rr] = (_Float16)wcol[(size_t)(ks * 32 + khi * 8 + rr) * 128];
      bf[nf][ks] = hb;
    }
  }

  f32x4 acc[8][2];
#pragma unroll
  for (int mf = 0; mf < 8; ++mf)
#pragma unroll
    for (int nf = 0; nf < 2; ++nf) acc[mf][nf] = (f32x4){0.f, 0.f, 0.f, 0.f};

#pragma unroll
  for (int mf = 0; mf < 8; ++mf) {
    const _Float16* ar = &sA[mf * 16 + lrow][khi * 8];
    half8 a0 = *(const half8*)(ar);
    half8 a1 = *(const half8*)(ar + 32);
    half8 a2 = *(const half8*)(ar + 64);
    half8 a3 = *(const half8*)(ar + 96);
    acc[mf][0] = __builtin_amdgcn_mfma_f32_16x16x32_f16(a0, bf[0][0], acc[mf][0], 0, 0, 0);
    acc[mf][1] = __builtin_amdgcn_mfma_f32_16x16x32_f16(a0, bf[1][0], acc[mf][1], 0, 0, 0);
    acc[mf][0] = __builtin_amdgcn_mfma_f32_16x16x32_f16(a1, bf[0][1], acc[mf][0], 0, 0, 0);
    acc[mf][1] = __builtin_amdgcn_mfma_f32_16x16x32_f16(a1, bf[1][1], acc[mf][1], 0, 0, 0);
    acc[mf][0] = __builtin_amdgcn_mfma_f32_16x16x32_f16(a2, bf[0][2], acc[mf][0], 0, 0, 0);
    acc[mf][1] = __builtin_amdgcn_mfma_f32_16x16x32_f16(a2, bf[1][2], acc[mf][1], 0, 0, 0);
    acc[mf][0] = __builtin_amdgcn_mfma_f32_16x16x32_f16(a3, bf[0][3], acc[mf][0], 0, 0, 0);
    acc[mf][1] = __builtin_amdgcn_mfma_f32_16x16x32_f16(a3, bf[1][3], acc[mf][1], 0, 0, 0);
  }

#pragma unroll
  for (int mf = 0; mf < 8; ++mf) {
    int r0 = mf * 16 + khi * 4;
#pragma unroll
    for (int nf = 0; nf < 2; ++nf) {
      int ccol = nbase + nf * 16 + lrow;
#pragma unroll
      for (int reg = 0; reg < 4; ++reg) {
        int r = m0 + r0 + reg;
        if (r < M) C[(size_t)r * 128 + ccol] = __float2half(acc[mf][nf][reg]);
      }
    }
  }
}

// ============ aggregation: two nodes per wave, interleaved gather chains ============
// PROVEN (R4: 115 us @ 3.75 TB/s, pattern roofline -- confirmed by 3 falsifications:
// 2x concurrency flat (R2), barrier-phasing -2.2x (R3), channel-chunking -3.2x (R5)).
__global__ __launch_bounds__(256) void agg_kernel(const __half* __restrict__ h,
    const int* __restrict__ csrc,
    const int* __restrict__ offs, const int* __restrict__ cnt,
    const float* __restrict__ dis, const float* __restrict__ bias,
    float* __restrict__ out, int n) {
  int wave = threadIdx.x >> 6;
  int lane = threadIdx.x & 63;
  int i0 = (blockIdx.x * 4 + wave) * 2;
  if (i0 >= n) return;
  int i1 = i0 + 1;
  bool has1 = i1 < n;
  int c = lane * 2;

  int st0 = offs[i0];
  int m0  = cnt[i0];
  float d0 = dis[i0];
  int st1 = 0, m1 = 0;
  float d1 = 0.f;
  if (has1) { st1 = offs[i1]; m1 = cnt[i1]; d1 = dis[i1]; }

  float ax0 = 0.f, ay0 = 0.f, ax1 = 0.f, ay1 = 0.f;
  int mMax = m0 > m1 ? m0 : m1;

  for (int base = 0; base < mMax; base += 64) {
    int mcA = m0 - base; mcA = mcA < 0 ? 0 : (mcA > 64 ? 64 : mcA);
    int mcB = m1 - base; mcB = mcB < 0 ? 0 : (mcB > 64 ? 64 : mcB);
    int mc = mcA > mcB ? mcA : mcB;

    int sA = 0, sB = 0;
    float wA = 0.f, wB = 0.f;
    if (lane < mcA) sA = csrc[st0 + base + lane];
    if (lane < mcB) sB = csrc[st1 + base + lane];
    if (lane < mcA) wA = dis[sA] * d0;
    if (lane < mcB) wB = dis[sB] * d1;

    int j = 0;
    for (; j + 4 <= mc; j += 4) {
      int   a0 = __shfl(sA, j);
      int   a1 = __shfl(sA, j + 1);
      int   a2 = __shfl(sA, j + 2);
      int   a3 = __shfl(sA, j + 3);
      int   b0 = __shfl(sB, j);
      int   b1 = __shfl(sB, j + 1);
      int   b2 = __shfl(sB, j + 2);
      int   b3 = __shfl(sB, j + 3);
      float u0 = __shfl(wA, j);
      float u1 = __shfl(wA, j + 1);
      float u2 = __shfl(wA, j + 2);
      float u3 = __shfl(wA, j + 3);
      float v0 = __shfl(wB, j);
      float v1 = __shfl(wB, j + 1);
      float v2 = __shfl(wB, j + 2);
      float v3 = __shfl(wB, j + 3);
      float2 hA0 = __half22float2(*(const __half2*)(h + ((size_t)a0 << 7) + c));
      float2 hA1 = __half22float2(*(const __half2*)(h + ((size_t)a1 << 7) + c));
      float2 hA2 = __half22float2(*(const __half2*)(h + ((size_t)a2 << 7) + c));
      float2 hA3 = __half22float2(*(const __half2*)(h + ((size_t)a3 << 7) + c));
      float2 hB0 = __half22float2(*(const __half2*)(h + ((size_t)b0 << 7) + c));
      float2 hB1 = __half22float2(*(const __half2*)(h + ((size_t)b1 << 7) + c));
      float2 hB2 = __half22float2(*(const __half2*)(h + ((size_t)b2 << 7) + c));
      float2 hB3 = __half22float2(*(const __half2*)(h + ((size_t)b3 << 7) + c));
      ax0 = fmaf(hA0.x, u0, ax0); ay0 = fmaf(hA0.y, u0, ay0);
      ax0 = fmaf(hA1.x, u1, ax0); ay0 = fmaf(hA1.y, u1, ay0);
      ax0 = fmaf(hA2.x, u2, ax0); ay0 = fmaf(hA2.y, u2, ay0);
      ax0 = fmaf(hA3.x, u3, ax0); ay0 = fmaf(hA3.y, u3, ay0);
      ax1 = fmaf(hB0.x, v0, ax1); ay1 = fmaf(hB0.y, v0, ay1);
      ax1 = fmaf(hB1.x, v1, ax1); ay1 = fmaf(hB1.y, v1, ay1);
      ax1 = fmaf(hB2.x, v2, ax1); ay1 = fmaf(hB2.y, v2, ay1);
      ax1 = fmaf(hB3.x, v3, ax1); ay1 = fmaf(hB3.y, v3, ay1);
    }
    for (; j < mc; ++j) {
      int   a0 = __shfl(sA, j);
      int   b0 = __shfl(sB, j);
      float u0 = __shfl(wA, j);
      float v0 = __shfl(wB, j);
      float2 hA0 = __half22float2(*(const __half2*)(h + ((size_t)a0 << 7) + c));
      float2 hB0 = __half22float2(*(const __half2*)(h + ((size_t)b0 << 7) + c));
      ax0 = fmaf(hA0.x, u0, ax0); ay0 = fmaf(hA0.y, u0, ay0);
      ax1 = fmaf(hB0.x, v0, ax1); ay1 = fmaf(hB0.y, v0, ay1);
    }
  }

  float2 bv = *(const float2*)(bias + c);
  {
    float dd = d0 * d0;
    float2 hs = __half22float2(*(const __half2*)(h + ((size_t)i0 << 7) + c));
    float vx = fmaf(hs.x, dd, ax0) + bv.x;
    float vy = fmaf(hs.y, dd, ay0) + bv.y;
    *(float2*)(out + (size_t)i0 * 128 + c) = make_float2(fmaxf(vx, 0.f), fmaxf(vy, 0.f));
  }
  if (has1) {
    float dd = d1 * d1;
    float2 hs = __half22float2(*(const __half2*)(h + ((size_t)i1 << 7) + c));
    float vx = fmaf(hs.x, dd, ax1) + bv.x;
    float vy = fmaf(hs.y, dd, ay1) + bv.y;
    *(float2*)(out + (size_t)i1 * 128 + c) = make_float2(fmaxf(vx, 0.f), fmaxf(vy, 0.f));
  }
}

// ============ heads: pack 3x[128,20] weights into [128,64] (cols 60..63 zero) ============
__global__ void pack_heads_w(const float* __restrict__ piW, const float* __restrict__ muW,
                             const float* __restrict__ lsW, float* __restrict__ W64) {
  int i = blockIdx.x * 256 + threadIdx.x;
  if (i >= 128 * 64) return;
  int k = i >> 6, j = i & 63;
  float v = 0.f;
  if (j < 20)      v = piW[k * 20 + j];
  else if (j < 40) v = muW[k * 20 + (j - 20)];
  else if (j < 60) v = lsW[k * 20 + (j - 40)];
  W64[i] = v;
}

// ============ heads GEMM: out60[M,64] = A[M,128] @ W64[128,64] ============
#define KC 64
__global__ __launch_bounds__(256) void gemm_heads(const float* __restrict__ A,
                                                  const float* __restrict__ B,
                                                  float* __restrict__ C, int M) {
  __shared__ float sA[64][KC + 4];
  __shared__ float sB[KC][68];
  int tid = threadIdx.x;
  int m0 = blockIdx.x * 64;
  int tr = tid >> 4;   // 0..15
  int tc = tid & 15;   // 0..15
  float acc[4][4];
#pragma unroll
  for (int i = 0; i < 4; ++i)
#pragma unroll
    for (int j = 0; j < 4; ++j) acc[i][j] = 0.f;

  for (int k0 = 0; k0 < 128; k0 += KC) {
#pragma unroll
    for (int q = 0; q < 4; ++q) {
      int idx = q * 256 + tid;
      int r = idx >> 4;
      int kk = (idx & 15) << 2;
      float4 v = make_float4(0.f, 0.f, 0.f, 0.f);
      if (m0 + r < M) v = *(const float4*)(A + (size_t)(m0 + r) * 128 + k0 + kk);
      *(float4*)(&sA[r][kk]) = v;
    }
#pragma unroll
    for (int q = 0; q < 4; ++q) {
      int idx = q * 256 + tid;
      int kk = idx >> 4;
      int nn = (idx & 15) << 2;
      *(float4*)(&sB[kk][nn]) = *(const float4*)(B + (size_t)(k0 + kk) * 64 + nn);
    }
    __syncthreads();
#pragma unroll 4
    for (int k = 0; k < KC; k += 4) {
      float4 a0 = *(const float4*)(&sA[tr][k]);
      float4 a1 = *(const float4*)(&sA[tr + 16][k]);
      float4 a2 = *(const float4*)(&sA[tr + 32][k]);
      float4 a3 = *(const float4*)(&sA[tr + 48][k]);
#pragma unroll
      for (int u = 0; u < 4; ++u) {
        float4 b = *(const float4*)(&sB[k + u][tc * 4]);
        float av[4] = {((const float*)&a0)[u], ((const float*)&a1)[u],
                       ((const float*)&a2)[u], ((const float*)&a3)[u]};
#pragma unroll
        for (int i = 0; i < 4; ++i) {
          acc[i][0] = fmaf(av[i], b.x, acc[i][0]);
          acc[i][1] = fmaf(av[i], b.y, acc[i][1]);
          acc[i][2] = fmaf(av[i], b.z, acc[i][2]);
          acc[i][3] = fmaf(av[i], b.w, acc[i][3]);
        }
      }
    }
    __syncthreads();
  }
#pragma unroll
  for (int i = 0; i < 4; ++i) {
    int r = m0 + tr + 16 * i;
    if (r < M)
      *(float4*)(C + (size_t)r * 64 + tc * 4) =
          make_float4(acc[i][0], acc[i][1], acc[i][2], acc[i][3]);
  }
}

// ============ heads postpass: bias + softmax(20) + scatter ============
__global__ __launch_bounds__(256) void heads_post(const float* __restrict__ out60,
    const float* __restrict__ pib, const float* __restrict__ mub,
    const float* __restrict__ lsb, float* __restrict__ out, int n) {
  int wave = threadIdx.x >> 6, lane = threadIdx.x & 63;
  int node = blockIdx.x * 4 + wave;
  if (node >= n) return;
  float v = 0.f;
  if (lane < 60) {
    v = out60[(size_t)node * 64 + lane];
    v += (lane < 20) ? pib[lane] : (lane < 40) ? mub[lane - 20] : lsb[lane - 40];
  }
  float pv = (lane < 20) ? v : -__builtin_inff();
  float mx = pv;
  for (int o = 16; o > 0; o >>= 1) mx = fmaxf(mx, __shfl_down(mx, o, 32));
  mx = __shfl(mx, 0, 32);
  float ev = (lane < 20) ? expf(v - mx) : 0.f;
  float sm = ev;
  for (int o = 16; o > 0; o >>= 1) sm += __shfl_down(sm, o, 32);
  sm = __shfl(sm, 0, 32);

  size_t base = (size_t)n * NG;
  if (lane < 20)      out[(size_t)node * NG + lane] = ev / sm;
  else if (lane < 40) out[base + (size_t)node * NG + (lane - 20)] = v;
  else if (lane < 60) out[2 * base + (size_t)node * NG + (lane - 40)] = v;
}

extern "C" void kernel_launch(void* const* d_in, const int* in_sizes, int n_in,
                              void* d_out, int out_size, void* d_ws, size_t ws_size,
                              hipStream_t stream) {
  const float* x   = (const float*)d_in[0];
  const int*   ei  = (const int*)d_in[1];
  const float* W1  = (const float*)d_in[2];
  const float* b1  = (const float*)d_in[3];
  const float* W2  = (const float*)d_in[4];
  const float* b2  = (const float*)d_in[5];
  const float* piW = (const float*)d_in[6];
  const float* pib = (const float*)d_in[7];
  const float* muW = (const float*)d_in[8];
  const float* mub = (const float*)d_in[9];
  const float* lsW = (const float*)d_in[10];
  const float* lsb = (const float*)d_in[11];
  float* out = (float*)d_out;

  const int N = in_sizes[0] / IN_DIM;
  const int E = in_sizes[1] / 2;
  const int* src = ei;
  const int* dst = ei + E;

  const int NBC  = (N + 255) >> 8;          // 391 coarse bins
  const int nblk = (E + T - 1) / T;         // 782 level-1 blocks
  const int ST   = NBC + 1;

  // workspace layout (~70 MB)
  char* p = (char*)d_ws;
  char* regionH = p;                        p += (size_t)N * HID * sizeof(__half);
  __half* h16  = (__half*)regionH;
  float* out60 = (float*)regionH;
  char* regionR = p;
  size_t szR = (size_t)N * HID * sizeof(float);
  size_t szT = (size_t)E * sizeof(int);
  p += (szR > szT ? szR : szT);
  int*   tmp    = (int*)regionR;
  float* bufB   = (float*)regionR;
  int*   csrc   = (int*)p;                  p += (size_t)E * sizeof(int);
  int*   bofs   = (int*)p;                  p += (size_t)nblk * ST * sizeof(int);
  int*   bintot = (int*)p;                  p += (size_t)MAXB * sizeof(int);
  int*   binbase= (int*)p;                  p += (size_t)MAXB * sizeof(int);
  int*   cnt    = (int*)p;                  p += (size_t)N * sizeof(int);
  int*   offs   = (int*)p;                  p += (size_t)N * sizeof(int);
  float* dis    = (float*)p;                p += (size_t)N * sizeof(float);
  float* W64    = (float*)p;                p += (size_t)128 * 64 * sizeof(float);

  // ---- CSR build ----
  zero_ints<<<(NBC + 255) / 256, 256, 0, stream>>>(bintot, NBC);
  binsort1<<<nblk, 512, 0, stream>>>(src, dst, tmp, bofs, bintot, NBC, E);
  binscan<<<1, 512, 0, stream>>>(bintot, binbase, NBC);
  binsort2<<<NBC, 1024, 0, stream>>>(tmp, bofs, binbase, csrc, cnt, dis, offs,
                                     NBC, nblk, N);
  pack_heads_w<<<(128 * 64 + 255) / 256, 256, 0, stream>>>(piW, muW, lsW, W64);

  const int NB8 = (N + 7) / 8;       // agg: 2 nodes/wave, 4 waves/block
  const int NBG = (N + 127) / 128;   // mfma gemm: 128 rows/block

  // ---- layers ----
  gemm128_mfma<<<NBG, 256, 0, stream>>>(x, W1, h16, N);
  agg_kernel<<<NB8, 256, 0, stream>>>(h16, csrc, offs, cnt, dis, b1, bufB, N);
  gemm128_mfma<<<NBG, 256, 0, stream>>>(bufB, W2, h16, N);
  agg_kernel<<<NB8, 256, 0, stream>>>(h16, csrc, offs, cnt, dis, b2, bufB, N);

  // ---- heads ----
  gemm_heads<<<(N + 63) / 64, 256, 0, stream>>>(bufB, W64, out60, N);
  heads_post<<<(N + 3) / 4, 256, 0, stream>>>(out60, pib, mub, lsb, out, N);
}

// Round 8
// 547.303 us; speedup vs baseline: 1.9157x; 1.0055x over previous
//
#include <hip/hip_runtime.h>
#include <hip/hip_fp16.h>
#include <cstdint>
#include <cstddef>

#define IN_DIM 128
#define HID    128
#define NG     20
#define T      4096        // edges per binsort1 block
#define MAXB   400         // max coarse bins (N <= 102400)

typedef _Float16 half8 __attribute__((ext_vector_type(8)));
typedef _Float16 half4 __attribute__((ext_vector_type(4)));
typedef float    f32x4 __attribute__((ext_vector_type(4)));

__global__ void zero_ints(int* __restrict__ a, int n) {
  int i = blockIdx.x * blockDim.x + threadIdx.x;
  if (i < n) a[i] = 0;
}

// ============ level 1: block-local sort into coarse bins (256 nodes/bin) ============
__global__ __launch_bounds__(512) void binsort1(const int* __restrict__ src,
    const int* __restrict__ dst, int* __restrict__ tmp, int* __restrict__ bofs,
    int* __restrict__ bintot, int NBC, int E) {
  __shared__ int lhist[MAXB];
  __shared__ int lscan[512];
  __shared__ int lcur[MAXB];
  __shared__ int sbuf[T];
  int tid = threadIdx.x;
  int tile0 = blockIdx.x * T;
  int m = E - tile0; if (m > T) m = T;

  for (int i = tid; i < NBC; i += 512) lhist[i] = 0;
  __syncthreads();

  int dreg[8];
#pragma unroll
  for (int j = 0; j < 8; ++j) {
    int idx = j * 512 + tid;
    dreg[j] = -1;
    if (idx < m) {
      int d = dst[tile0 + idx];
      dreg[j] = d;
      atomicAdd(&lhist[d >> 8], 1);
    }
  }
  __syncthreads();

  int v = (tid < NBC) ? lhist[tid] : 0;
  lscan[tid] = v;
  __syncthreads();
  for (int o = 1; o < 512; o <<= 1) {
    int t = (tid >= o) ? lscan[tid - o] : 0;
    __syncthreads();
    lscan[tid] += t;
    __syncthreads();
  }
  if (tid < NBC) lcur[tid] = lscan[tid] - v;
  __syncthreads();

  int ST = NBC + 1;
  for (int i = tid; i < NBC; i += 512) bofs[(size_t)blockIdx.x * ST + i] = lcur[i];
  if (tid == 0) bofs[(size_t)blockIdx.x * ST + NBC] = m;
  for (int i = tid; i < NBC; i += 512)
    if (lhist[i]) atomicAdd(&bintot[i], lhist[i]);
  __syncthreads();

#pragma unroll
  for (int j = 0; j < 8; ++j) {
    int idx = j * 512 + tid;
    if (idx < m) {
      int d = dreg[j];
      int s = src[tile0 + idx];
      int slot = atomicAdd(&lcur[d >> 8], 1);
      sbuf[slot] = ((d & 255) << 17) | s;
    }
  }
  __syncthreads();

  int nv = m >> 2;
  int4* out4 = (int4*)(tmp + tile0);
  const int4* sb4 = (const int4*)sbuf;
  for (int i = tid; i < nv; i += 512) out4[i] = sb4[i];
  for (int i = (nv << 2) + tid; i < m; i += 512) tmp[tile0 + i] = sbuf[i];
}

// ============ scan bin totals -> bin bases (1 block) ============
__global__ __launch_bounds__(512) void binscan(const int* __restrict__ bintot,
                                               int* __restrict__ binbase, int NBC) {
  __shared__ int s[512];
  int tid = threadIdx.x;
  int v = (tid < NBC) ? bintot[tid] : 0;
  s[tid] = v;
  __syncthreads();
  for (int o = 1; o < 512; o <<= 1) {
    int t = (tid >= o) ? s[tid - o] : 0;
    __syncthreads();
    s[tid] += t;
    __syncthreads();
  }
  if (tid < NBC) binbase[tid] = s[tid] - v;
}

// ============ level 2: one block per coarse bin -> final CSR + node meta ============
__global__ __launch_bounds__(1024) void binsort2(const int* __restrict__ tmp,
    const int* __restrict__ bofs, const int* __restrict__ binbase,
    int* __restrict__ csrc, int* __restrict__ cnt, float* __restrict__ dis,
    int* __restrict__ offs, int NBC, int nblk, int N) {
  __shared__ int lcnt[256];
  __shared__ int lsc[256];
  __shared__ int lcur2[256];
  int b = blockIdx.x;
  int tid = threadIdx.x;
  if (tid < 256) lcnt[tid] = 0;
  __syncthreads();
  int ST = NBC + 1;
  for (int r = tid; r < nblk; r += 1024) {
    int s = bofs[(size_t)r * ST + b];
    int e2 = bofs[(size_t)r * ST + b + 1];
    int base = r * T;
    for (int k = s; k < e2; ++k)
      atomicAdd(&lcnt[tmp[base + k] >> 17], 1);
  }
  __syncthreads();
  if (tid < 256) lsc[tid] = lcnt[tid];
  __syncthreads();
  for (int o = 1; o < 256; o <<= 1) {
    int t = 0;
    if (tid < 256 && tid >= o) t = lsc[tid - o];
    __syncthreads();
    if (tid < 256) lsc[tid] += t;
    __syncthreads();
  }
  int gbase = binbase[b];
  if (tid < 256) {
    int excl = lsc[tid] - lcnt[tid];
    lcur2[tid] = gbase + excl;
    int node = (b << 8) + tid;
    if (node < N) {
      cnt[node] = lcnt[tid];
      dis[node] = rsqrtf((float)lcnt[tid] + 1.0f);
      offs[node] = gbase + excl;
    }
  }
  __syncthreads();
  for (int r = tid; r < nblk; r += 1024) {
    int s = bofs[(size_t)r * ST + b];
    int e2 = bofs[(size_t)r * ST + b + 1];
    int base = r * T;
    for (int k = s; k < e2; ++k) {
      int rec = tmp[base + k];
      int pos = atomicAdd(&lcur2[rec >> 17], 1);
      csrc[pos] = rec & 0x1FFFF;
    }
  }
}

// ============ MFMA GEMM, f16 out: C16[M,128] = A[M,128] @ B[128,128] ============
// v2: B-fragment chunk prefetch (ks=0 issued BEFORE A staging, hidden under the
// staging barrier drain; subsequent ks double-buffered between MFMA groups) --
// breaks the 64-deep serial strided B-load chain that 3 blocks/CU can't hide.
// F16IN variant: input already f16 (agg f16-out path) -> straight half8 staging.
template<bool F16IN>
__global__ __launch_bounds__(256) void gemm128_mfma(const void* __restrict__ Av,
                                                    const float* __restrict__ B,
                                                    __half* __restrict__ C, int M) {
  __shared__ _Float16 sA[128][136];
  const int tid = threadIdx.x;
  const int m0 = blockIdx.x * 128;
  const int wave = tid >> 6, lane = tid & 63;
  const int nbase = wave << 5;
  const int lrow = lane & 15;
  const int khi  = lane >> 4;
  const float* wcol = B + nbase + lrow;

  float bA[2][8], bB[2][8];
  // prefetch B chunk ks=0 before A staging (independent; L2-hot)
#pragma unroll
  for (int nf = 0; nf < 2; ++nf)
#pragma unroll
    for (int rr = 0; rr < 8; ++rr)
      bA[nf][rr] = wcol[(size_t)(khi * 8 + rr) * 128 + nf * 16];

  if constexpr (F16IN) {
    const __half* A = (const __half*)Av;
#pragma unroll
    for (int q = 0; q < 8; ++q) {
      int idx = q * 256 + tid;
      int r = idx >> 4;
      int cc = (idx & 15) << 3;
      half8 hv = {};
      if (m0 + r < M) hv = *(const half8*)(A + (size_t)(m0 + r) * 128 + cc);
      *(half8*)(&sA[r][cc]) = hv;
    }
  } else {
    const float* A = (const float*)Av;
#pragma unroll
    for (int q = 0; q < 16; ++q) {
      int idx = q * 256 + tid;
      int r = idx >> 5;
      int cc = (idx & 31) << 2;
      float4 v = make_float4(0.f, 0.f, 0.f, 0.f);
      if (m0 + r < M) v = *(const float4*)(A + (size_t)(m0 + r) * 128 + cc);
      half4 hv;
      hv[0] = (_Float16)v.x; hv[1] = (_Float16)v.y;
      hv[2] = (_Float16)v.z; hv[3] = (_Float16)v.w;
      *(half4*)(&sA[r][cc]) = hv;
    }
  }
  __syncthreads();

  f32x4 acc[8][2];
#pragma unroll
  for (int mf = 0; mf < 8; ++mf)
#pragma unroll
    for (int nf = 0; nf < 2; ++nf) acc[mf][nf] = (f32x4){0.f, 0.f, 0.f, 0.f};

  auto loadB = [&](float (&dst)[2][8], int ks) {
#pragma unroll
    for (int nf = 0; nf < 2; ++nf)
#pragma unroll
      for (int rr = 0; rr < 8; ++rr)
        dst[nf][rr] = wcol[(size_t)(ks * 32 + khi * 8 + rr) * 128 + nf * 16];
  };
  half8 bf0, bf1;
  auto cvtB = [&](float (&s)[2][8]) {
#pragma unroll
    for (int rr = 0; rr < 8; ++rr) {
      bf0[rr] = (_Float16)s[0][rr];
      bf1[rr] = (_Float16)s[1][rr];
    }
  };
  auto mfmas = [&](int ks) {
#pragma unroll
    for (int mf = 0; mf < 8; ++mf) {
      half8 a = *(const half8*)(&sA[mf * 16 + lrow][khi * 8 + ks * 32]);
      acc[mf][0] = __builtin_amdgcn_mfma_f32_16x16x32_f16(a, bf0, acc[mf][0], 0, 0, 0);
      acc[mf][1] = __builtin_amdgcn_mfma_f32_16x16x32_f16(a, bf1, acc[mf][1], 0, 0, 0);
    }
  };
  cvtB(bA); loadB(bB, 1); mfmas(0);
  cvtB(bB); loadB(bA, 2); mfmas(1);
  cvtB(bA); loadB(bB, 3); mfmas(2);
  cvtB(bB);               mfmas(3);

#pragma unroll
  for (int mf = 0; mf < 8; ++mf) {
    int r0 = mf * 16 + khi * 4;
#pragma unroll
    for (int nf = 0; nf < 2; ++nf) {
      int ccol = nbase + nf * 16 + lrow;
#pragma unroll
      for (int reg = 0; reg < 4; ++reg) {
        int r = m0 + r0 + reg;
        if (r < M) C[(size_t)r * 128 + ccol] = __float2half(acc[mf][nf][reg]);
      }
    }
  }
}

// ============ aggregation: two nodes per wave, interleaved gather chains ============
// PROVEN (115 us @ 3.75 TB/s pattern roofline -- 3 falsifications: 2x concurrency
// flat (R2), barrier-phasing -2.2x (R3), channel-chunking -3.2x (R5)). OutT=__half
// for layer 1: gemm2 converts to f16 anyway, so rounding point is identical but
// write traffic halves (writes share the saturated fabric budget).
template<typename OutT>
__global__ __launch_bounds__(256) void agg_kernel(const __half* __restrict__ h,
    const int* __restrict__ csrc,
    const int* __restrict__ offs, const int* __restrict__ cnt,
    const float* __restrict__ dis, const float* __restrict__ bias,
    OutT* __restrict__ out, int n) {
  int wave = threadIdx.x >> 6;
  int lane = threadIdx.x & 63;
  int i0 = (blockIdx.x * 4 + wave) * 2;
  if (i0 >= n) return;
  int i1 = i0 + 1;
  bool has1 = i1 < n;
  int c = lane * 2;

  int st0 = offs[i0];
  int m0  = cnt[i0];
  float d0 = dis[i0];
  int st1 = 0, m1 = 0;
  float d1 = 0.f;
  if (has1) { st1 = offs[i1]; m1 = cnt[i1]; d1 = dis[i1]; }

  float ax0 = 0.f, ay0 = 0.f, ax1 = 0.f, ay1 = 0.f;
  int mMax = m0 > m1 ? m0 : m1;

  for (int base = 0; base < mMax; base += 64) {
    int mcA = m0 - base; mcA = mcA < 0 ? 0 : (mcA > 64 ? 64 : mcA);
    int mcB = m1 - base; mcB = mcB < 0 ? 0 : (mcB > 64 ? 64 : mcB);
    int mc = mcA > mcB ? mcA : mcB;

    int sA = 0, sB = 0;
    float wA = 0.f, wB = 0.f;
    if (lane < mcA) sA = csrc[st0 + base + lane];
    if (lane < mcB) sB = csrc[st1 + base + lane];
    if (lane < mcA) wA = dis[sA] * d0;
    if (lane < mcB) wB = dis[sB] * d1;

    int j = 0;
    for (; j + 4 <= mc; j += 4) {
      int   a0 = __shfl(sA, j);
      int   a1 = __shfl(sA, j + 1);
      int   a2 = __shfl(sA, j + 2);
      int   a3 = __shfl(sA, j + 3);
      int   b0 = __shfl(sB, j);
      int   b1 = __shfl(sB, j + 1);
      int   b2 = __shfl(sB, j + 2);
      int   b3 = __shfl(sB, j + 3);
      float u0 = __shfl(wA, j);
      float u1 = __shfl(wA, j + 1);
      float u2 = __shfl(wA, j + 2);
      float u3 = __shfl(wA, j + 3);
      float v0 = __shfl(wB, j);
      float v1 = __shfl(wB, j + 1);
      float v2 = __shfl(wB, j + 2);
      float v3 = __shfl(wB, j + 3);
      float2 hA0 = __half22float2(*(const __half2*)(h + ((size_t)a0 << 7) + c));
      float2 hA1 = __half22float2(*(const __half2*)(h + ((size_t)a1 << 7) + c));
      float2 hA2 = __half22float2(*(const __half2*)(h + ((size_t)a2 << 7) + c));
      float2 hA3 = __half22float2(*(const __half2*)(h + ((size_t)a3 << 7) + c));
      float2 hB0 = __half22float2(*(const __half2*)(h + ((size_t)b0 << 7) + c));
      float2 hB1 = __half22float2(*(const __half2*)(h + ((size_t)b1 << 7) + c));
      float2 hB2 = __half22float2(*(const __half2*)(h + ((size_t)b2 << 7) + c));
      float2 hB3 = __half22float2(*(const __half2*)(h + ((size_t)b3 << 7) + c));
      ax0 = fmaf(hA0.x, u0, ax0); ay0 = fmaf(hA0.y, u0, ay0);
      ax0 = fmaf(hA1.x, u1, ax0); ay0 = fmaf(hA1.y, u1, ay0);
      ax0 = fmaf(hA2.x, u2, ax0); ay0 = fmaf(hA2.y, u2, ay0);
      ax0 = fmaf(hA3.x, u3, ax0); ay0 = fmaf(hA3.y, u3, ay0);
      ax1 = fmaf(hB0.x, v0, ax1); ay1 = fmaf(hB0.y, v0, ay1);
      ax1 = fmaf(hB1.x, v1, ax1); ay1 = fmaf(hB1.y, v1, ay1);
      ax1 = fmaf(hB2.x, v2, ax1); ay1 = fmaf(hB2.y, v2, ay1);
      ax1 = fmaf(hB3.x, v3, ax1); ay1 = fmaf(hB3.y, v3, ay1);
    }
    for (; j < mc; ++j) {
      int   a0 = __shfl(sA, j);
      int   b0 = __shfl(sB, j);
      float u0 = __shfl(wA, j);
      float v0 = __shfl(wB, j);
      float2 hA0 = __half22float2(*(const __half2*)(h + ((size_t)a0 << 7) + c));
      float2 hB0 = __half22float2(*(const __half2*)(h + ((size_t)b0 << 7) + c));
      ax0 = fmaf(hA0.x, u0, ax0); ay0 = fmaf(hA0.y, u0, ay0);
      ax1 = fmaf(hB0.x, v0, ax1); ay1 = fmaf(hB0.y, v0, ay1);
    }
  }

  float2 bv = *(const float2*)(bias + c);
  {
    float dd = d0 * d0;
    float2 hs = __half22float2(*(const __half2*)(h + ((size_t)i0 << 7) + c));
    float vx = fmaxf(fmaf(hs.x, dd, ax0) + bv.x, 0.f);
    float vy = fmaxf(fmaf(hs.y, dd, ay0) + bv.y, 0.f);
    if constexpr (sizeof(OutT) == 2) {
      *(__half2*)((__half*)out + (size_t)i0 * 128 + c) = __floats2half2_rn(vx, vy);
    } else {
      *(float2*)((float*)out + (size_t)i0 * 128 + c) = make_float2(vx, vy);
    }
  }
  if (has1) {
    float dd = d1 * d1;
    float2 hs = __half22float2(*(const __half2*)(h + ((size_t)i1 << 7) + c));
    float vx = fmaxf(fmaf(hs.x, dd, ax1) + bv.x, 0.f);
    float vy = fmaxf(fmaf(hs.y, dd, ay1) + bv.y, 0.f);
    if constexpr (sizeof(OutT) == 2) {
      *(__half2*)((__half*)out + (size_t)i1 * 128 + c) = __floats2half2_rn(vx, vy);
    } else {
      *(float2*)((float*)out + (size_t)i1 * 128 + c) = make_float2(vx, vy);
    }
  }
}

// ============ heads: pack 3x[128,20] weights into [128,64] (cols 60..63 zero) ============
__global__ void pack_heads_w(const float* __restrict__ piW, const float* __restrict__ muW,
                             const float* __restrict__ lsW, float* __restrict__ W64) {
  int i = blockIdx.x * 256 + threadIdx.x;
  if (i >= 128 * 64) return;
  int k = i >> 6, j = i & 63;
  float v = 0.f;
  if (j < 20)      v = piW[k * 20 + j];
  else if (j < 40) v = muW[k * 20 + (j - 20)];
  else if (j < 60) v = lsW[k * 20 + (j - 40)];
  W64[i] = v;
}

// ============ fused heads: GEMM [M,128]@[128,64] + bias + softmax(20) + scatter ====
// Fuses the old gemm_heads + heads_post: removes one launch and the 51 MB out60
// round trip. Barriers are fine here (compute kernel, not a gather kernel).
#define KC 64
__global__ __launch_bounds__(256) void heads_fused(const float* __restrict__ A,
    const float* __restrict__ B, const float* __restrict__ pib,
    const float* __restrict__ mub, const float* __restrict__ lsb,
    float* __restrict__ out, int n) {
  __shared__ float sA[64][KC + 4];
  __shared__ float sB[KC][68];
  __shared__ float sOut[64][68];
  int tid = threadIdx.x;
  int m0 = blockIdx.x * 64;
  int tr = tid >> 4;   // 0..15
  int tc = tid & 15;   // 0..15
  float acc[4][4];
#pragma unroll
  for (int i = 0; i < 4; ++i)
#pragma unroll
    for (int j = 0; j < 4; ++j) acc[i][j] = 0.f;

  for (int k0 = 0; k0 < 128; k0 += KC) {
#pragma unroll
    for (int q = 0; q < 4; ++q) {
      int idx = q * 256 + tid;
      int r = idx >> 4;
      int kk = (idx & 15) << 2;
      float4 v = make_float4(0.f, 0.f, 0.f, 0.f);
      if (m0 + r < n) v = *(const float4*)(A + (size_t)(m0 + r) * 128 + k0 + kk);
      *(float4*)(&sA[r][kk]) = v;
    }
#pragma unroll
    for (int q = 0; q < 4; ++q) {
      int idx = q * 256 + tid;
      int kk = idx >> 4;
      int nn = (idx & 15) << 2;
      *(float4*)(&sB[kk][nn]) = *(const float4*)(B + (size_t)(k0 + kk) * 64 + nn);
    }
    __syncthreads();
#pragma unroll 4
    for (int k = 0; k < KC; k += 4) {
      float4 a0 = *(const float4*)(&sA[tr][k]);
      float4 a1 = *(const float4*)(&sA[tr + 16][k]);
      float4 a2 = *(const float4*)(&sA[tr + 32][k]);
      float4 a3 = *(const float4*)(&sA[tr + 48][k]);
#pragma unroll
      for (int u = 0; u < 4; ++u) {
        float4 b = *(const float4*)(&sB[k + u][tc * 4]);
        float av[4] = {((const float*)&a0)[u], ((const float*)&a1)[u],
                       ((const float*)&a2)[u], ((const float*)&a3)[u]};
#pragma unroll
        for (int i = 0; i < 4; ++i) {
          acc[i][0] = fmaf(av[i], b.x, acc[i][0]);
          acc[i][1] = fmaf(av[i], b.y, acc[i][1]);
          acc[i][2] = fmaf(av[i], b.z, acc[i][2]);
          acc[i][3] = fmaf(av[i], b.w, acc[i][3]);
        }
      }
    }
    __syncthreads();
  }

#pragma unroll
  for (int i = 0; i < 4; ++i)
#pragma unroll
    for (int j = 0; j < 4; ++j) sOut[tr + 16 * i][tc * 4 + j] = acc[i][j];
  __syncthreads();

  // softmax(20) + scatter: wave w handles rows w*16 .. w*16+15 (heads_post logic)
  int wave = tid >> 6, lane = tid & 63;
  size_t nb = (size_t)n * NG;
  for (int t = 0; t < 16; ++t) {
    int rr = wave * 16 + t;
    int node = m0 + rr;
    if (node >= n) break;   // wave-uniform
    float v = 0.f;
    if (lane < 60) {
      v = sOut[rr][lane];
      v += (lane < 20) ? pib[lane] : (lane < 40) ? mub[lane - 20] : lsb[lane - 40];
    }
    float pv = (lane < 20) ? v : -__builtin_inff();
    float mx = pv;
    for (int o = 16; o > 0; o >>= 1) mx = fmaxf(mx, __shfl_down(mx, o, 32));
    mx = __shfl(mx, 0, 32);
    float ev = (lane < 20) ? expf(v - mx) : 0.f;
    float sm = ev;
    for (int o = 16; o > 0; o >>= 1) sm += __shfl_down(sm, o, 32);
    sm = __shfl(sm, 0, 32);
    if (lane < 20)      out[(size_t)node * NG + lane] = ev / sm;
    else if (lane < 40) out[nb + (size_t)node * NG + (lane - 20)] = v;
    else if (lane < 60) out[2 * nb + (size_t)node * NG + (lane - 40)] = v;
  }
}

extern "C" void kernel_launch(void* const* d_in, const int* in_sizes, int n_in,
                              void* d_out, int out_size, void* d_ws, size_t ws_size,
                              hipStream_t stream) {
  const float* x   = (const float*)d_in[0];
  const int*   ei  = (const int*)d_in[1];
  const float* W1  = (const float*)d_in[2];
  const float* b1  = (const float*)d_in[3];
  const float* W2  = (const float*)d_in[4];
  const float* b2  = (const float*)d_in[5];
  const float* piW = (const float*)d_in[6];
  const float* pib = (const float*)d_in[7];
  const float* muW = (const float*)d_in[8];
  const float* mub = (const float*)d_in[9];
  const float* lsW = (const float*)d_in[10];
  const float* lsb = (const float*)d_in[11];
  float* out = (float*)d_out;

  const int N = in_sizes[0] / IN_DIM;
  const int E = in_sizes[1] / 2;
  const int* src = ei;
  const int* dst = ei + E;

  const int NBC  = (N + 255) >> 8;          // 391 coarse bins
  const int nblk = (E + T - 1) / T;         // 782 level-1 blocks
  const int ST   = NBC + 1;

  // workspace layout
  char* p = (char*)d_ws;
  char* regionH = p;                        p += (size_t)N * HID * sizeof(__half);
  __half* h16  = (__half*)regionH;
  char* regionR = p;                        // tmp -> bufB16 -> bufB (sequential reuse)
  size_t szR = (size_t)N * HID * sizeof(float);
  size_t szT = (size_t)E * sizeof(int);
  p += (szR > szT ? szR : szT);
  int*    tmp    = (int*)regionR;
  __half* bufB16 = (__half*)regionR;
  float*  bufB   = (float*)regionR;
  int*   csrc   = (int*)p;                  p += (size_t)E * sizeof(int);
  int*   bofs   = (int*)p;                  p += (size_t)nblk * ST * sizeof(int);
  int*   bintot = (int*)p;                  p += (size_t)MAXB * sizeof(int);
  int*   binbase= (int*)p;                  p += (size_t)MAXB * sizeof(int);
  int*   cnt    = (int*)p;                  p += (size_t)N * sizeof(int);
  int*   offs   = (int*)p;                  p += (size_t)N * sizeof(int);
  float* dis    = (float*)p;                p += (size_t)N * sizeof(float);
  float* W64    = (float*)p;                p += (size_t)128 * 64 * sizeof(float);

  // ---- CSR build ----
  zero_ints<<<(NBC + 255) / 256, 256, 0, stream>>>(bintot, NBC);
  binsort1<<<nblk, 512, 0, stream>>>(src, dst, tmp, bofs, bintot, NBC, E);
  binscan<<<1, 512, 0, stream>>>(bintot, binbase, NBC);
  binsort2<<<NBC, 1024, 0, stream>>>(tmp, bofs, binbase, csrc, cnt, dis, offs,
                                     NBC, nblk, N);
  pack_heads_w<<<(128 * 64 + 255) / 256, 256, 0, stream>>>(piW, muW, lsW, W64);

  const int NB8 = (N + 7) / 8;       // agg: 2 nodes/wave, 4 waves/block
  const int NBG = (N + 127) / 128;   // mfma gemm: 128 rows/block

  // ---- layers ----
  gemm128_mfma<false><<<NBG, 256, 0, stream>>>(x, W1, h16, N);
  agg_kernel<__half><<<NB8, 256, 0, stream>>>(h16, csrc, offs, cnt, dis, b1,
                                              bufB16, N);
  gemm128_mfma<true><<<NBG, 256, 0, stream>>>(bufB16, W2, h16, N);
  agg_kernel<float><<<NB8, 256, 0, stream>>>(h16, csrc, offs, cnt, dis, b2,
                                             bufB, N);

  // ---- heads (GEMM + softmax fused) ----
  heads_fused<<<(N + 63) / 64, 256, 0, stream>>>(bufB, W64, pib, mub, lsb, out, N);
}

// Round 9
// 544.594 us; speedup vs baseline: 1.9253x; 1.0050x over previous
//
#include <hip/hip_runtime.h>
#include <hip/hip_fp16.h>
#include <cstdint>
#include <cstddef>

#define IN_DIM 128
#define HID    128
#define NG     20
#define T      4096        // edges per binsort1 block
#define MAXB   400         // max coarse bins (N <= 102400)
#define SMEM_BYTES 34816   // max(gemm sA 128*136*2, binsort1 21632, binsort2 3072)

typedef _Float16 half8 __attribute__((ext_vector_type(8)));
typedef _Float16 half4 __attribute__((ext_vector_type(4)));
typedef float    f32x4 __attribute__((ext_vector_type(4)));

__global__ void zero_ints(int* __restrict__ a, int n) {
  int i = blockIdx.x * blockDim.x + threadIdx.x;
  if (i < n) a[i] = 0;
}

// ============ binsort1 body: block-local sort into coarse bins (256 threads) ============
__device__ __forceinline__ void binsort1_body(const int* __restrict__ src,
    const int* __restrict__ dst, int* __restrict__ tmp, int* __restrict__ bofs,
    int* __restrict__ bintot, int NBC, int E, int blk, char* smemc) {
  int* lhist = (int*)smemc;          // MAXB
  int* lscan = lhist + MAXB;         // 512
  int* lcur  = lscan + 512;          // MAXB
  int* sbuf  = lcur + MAXB;          // T
  int tid = threadIdx.x;
  int tile0 = blk * T;
  int m = E - tile0; if (m > T) m = T;

  for (int i = tid; i < NBC; i += 256) lhist[i] = 0;
  __syncthreads();

  int dreg[16];
#pragma unroll
  for (int j = 0; j < 16; ++j) {
    int idx = j * 256 + tid;
    dreg[j] = -1;
    if (idx < m) {
      int d = dst[tile0 + idx];
      dreg[j] = d;
      atomicAdd(&lhist[d >> 8], 1);
    }
  }
  __syncthreads();

  int v0 = (tid < NBC) ? lhist[tid] : 0;
  int v1 = (256 + tid < NBC) ? lhist[256 + tid] : 0;
  lscan[tid] = v0; lscan[256 + tid] = v1;
  __syncthreads();
  for (int o = 1; o < 512; o <<= 1) {
    int a0 = (tid >= o) ? lscan[tid - o] : 0;
    int a1 = (256 + tid >= o) ? lscan[256 + tid - o] : 0;
    __syncthreads();
    lscan[tid] += a0; lscan[256 + tid] += a1;
    __syncthreads();
  }
  if (tid < NBC)       lcur[tid]       = lscan[tid] - v0;
  if (256 + tid < NBC) lcur[256 + tid] = lscan[256 + tid] - v1;
  __syncthreads();

  int ST = NBC + 1;
  for (int i = tid; i < NBC; i += 256) bofs[(size_t)blk * ST + i] = lcur[i];
  if (tid == 0) bofs[(size_t)blk * ST + NBC] = m;
  for (int i = tid; i < NBC; i += 256)
    if (lhist[i]) atomicAdd(&bintot[i], lhist[i]);
  __syncthreads();

#pragma unroll
  for (int j = 0; j < 16; ++j) {
    int idx = j * 256 + tid;
    if (idx < m) {
      int d = dreg[j];
      int s = src[tile0 + idx];
      int slot = atomicAdd(&lcur[d >> 8], 1);
      sbuf[slot] = ((d & 255) << 17) | s;
    }
  }
  __syncthreads();

  int nv = m >> 2;
  int4* out4 = (int4*)(tmp + tile0);
  const int4* sb4 = (const int4*)sbuf;
  for (int i = tid; i < nv; i += 256) out4[i] = sb4[i];
  for (int i = (nv << 2) + tid; i < m; i += 256) tmp[tile0 + i] = sbuf[i];
}

// ============ binsort2 body: one block per coarse bin -> final CSR (256 threads) ======
__device__ __forceinline__ void binsort2_body(const int* __restrict__ tmp,
    const int* __restrict__ bofs, const int* __restrict__ binbase,
    int* __restrict__ csrc, int* __restrict__ cnt, float* __restrict__ dis,
    int* __restrict__ offs, int NBC, int nblk, int N, int b, char* smemc) {
  int* lcnt  = (int*)smemc;     // 256
  int* lsc   = lcnt + 256;      // 256
  int* lcur2 = lsc + 256;       // 256
  int tid = threadIdx.x;
  lcnt[tid] = 0;
  __syncthreads();
  int ST = NBC + 1;
  for (int r = tid; r < nblk; r += 256) {
    int s = bofs[(size_t)r * ST + b];
    int e2 = bofs[(size_t)r * ST + b + 1];
    int base = r * T;
    for (int k = s; k < e2; ++k)
      atomicAdd(&lcnt[tmp[base + k] >> 17], 1);
  }
  __syncthreads();
  int v = lcnt[tid];
  lsc[tid] = v;
  __syncthreads();
  for (int o = 1; o < 256; o <<= 1) {
    int t = (tid >= o) ? lsc[tid - o] : 0;
    __syncthreads();
    lsc[tid] += t;
    __syncthreads();
  }
  int gbase = binbase[b];
  int excl = lsc[tid] - v;
  lcur2[tid] = gbase + excl;
  int node = (b << 8) + tid;
  if (node < N) {
    cnt[node] = v;
    dis[node] = rsqrtf((float)v + 1.0f);
    offs[node] = gbase + excl;
  }
  __syncthreads();
  for (int r = tid; r < nblk; r += 256) {
    int s = bofs[(size_t)r * ST + b];
    int e2 = bofs[(size_t)r * ST + b + 1];
    int base = r * T;
    for (int k = s; k < e2; ++k) {
      int rec = tmp[base + k];
      int pos = atomicAdd(&lcur2[rec >> 17], 1);
      csrc[pos] = rec & 0x1FFFF;
    }
  }
}

// ============ MFMA GEMM body, f16 out: C16[128,128] tile = A[128,128] @ B[128,128] ====
template<bool F16IN>
__device__ __forceinline__ void gemm_body(const void* __restrict__ Av,
    const float* __restrict__ B, __half* __restrict__ C, int M, int m0,
    char* smemc) {
  _Float16 (*sA)[136] = (_Float16(*)[136])smemc;
  const int tid = threadIdx.x;
  const int wave = tid >> 6, lane = tid & 63;
  const int nbase = wave << 5;
  const int lrow = lane & 15;
  const int khi  = lane >> 4;
  const float* wcol = B + nbase + lrow;

  float bA[2][8], bB[2][8];
  // prefetch B chunk ks=0 before A staging (independent; L2-hot)
#pragma unroll
  for (int nf = 0; nf < 2; ++nf)
#pragma unroll
    for (int rr = 0; rr < 8; ++rr)
      bA[nf][rr] = wcol[(size_t)(khi * 8 + rr) * 128 + nf * 16];

  if constexpr (F16IN) {
    const __half* A = (const __half*)Av;
#pragma unroll
    for (int q = 0; q < 8; ++q) {
      int idx = q * 256 + tid;
      int r = idx >> 4;
      int cc = (idx & 15) << 3;
      half8 hv = {};
      if (m0 + r < M) hv = *(const half8*)(A + (size_t)(m0 + r) * 128 + cc);
      *(half8*)(&sA[r][cc]) = hv;
    }
  } else {
    const float* A = (const float*)Av;
#pragma unroll
    for (int q = 0; q < 16; ++q) {
      int idx = q * 256 + tid;
      int r = idx >> 5;
      int cc = (idx & 31) << 2;
      float4 v = make_float4(0.f, 0.f, 0.f, 0.f);
      if (m0 + r < M) v = *(const float4*)(A + (size_t)(m0 + r) * 128 + cc);
      half4 hv;
      hv[0] = (_Float16)v.x; hv[1] = (_Float16)v.y;
      hv[2] = (_Float16)v.z; hv[3] = (_Float16)v.w;
      *(half4*)(&sA[r][cc]) = hv;
    }
  }
  __syncthreads();

  f32x4 acc[8][2];
#pragma unroll
  for (int mf = 0; mf < 8; ++mf)
#pragma unroll
    for (int nf = 0; nf < 2; ++nf) acc[mf][nf] = (f32x4){0.f, 0.f, 0.f, 0.f};

  auto loadB = [&](float (&dst)[2][8], int ks) {
#pragma unroll
    for (int nf = 0; nf < 2; ++nf)
#pragma unroll
      for (int rr = 0; rr < 8; ++rr)
        dst[nf][rr] = wcol[(size_t)(ks * 32 + khi * 8 + rr) * 128 + nf * 16];
  };
  half8 bf0, bf1;
  auto cvtB = [&](float (&s)[2][8]) {
#pragma unroll
    for (int rr = 0; rr < 8; ++rr) {
      bf0[rr] = (_Float16)s[0][rr];
      bf1[rr] = (_Float16)s[1][rr];
    }
  };
  auto mfmas = [&](int ks) {
#pragma unroll
    for (int mf = 0; mf < 8; ++mf) {
      half8 a = *(const half8*)(&sA[mf * 16 + lrow][khi * 8 + ks * 32]);
      acc[mf][0] = __builtin_amdgcn_mfma_f32_16x16x32_f16(a, bf0, acc[mf][0], 0, 0, 0);
      acc[mf][1] = __builtin_amdgcn_mfma_f32_16x16x32_f16(a, bf1, acc[mf][1], 0, 0, 0);
    }
  };
  cvtB(bA); loadB(bB, 1); mfmas(0);
  cvtB(bB); loadB(bA, 2); mfmas(1);
  cvtB(bA); loadB(bB, 3); mfmas(2);
  cvtB(bB);               mfmas(3);

#pragma unroll
  for (int mf = 0; mf < 8; ++mf) {
    int r0 = mf * 16 + khi * 4;
#pragma unroll
    for (int nf = 0; nf < 2; ++nf) {
      int ccol = nbase + nf * 16 + lrow;
#pragma unroll
      for (int reg = 0; reg < 4; ++reg) {
        int r = m0 + r0 + reg;
        if (r < M) C[(size_t)r * 128 + ccol] = __float2half(acc[mf][nf][reg]);
      }
    }
  }
}

// standalone gemm (layer 2, serial chain)
__global__ __launch_bounds__(256) void gemm128_mfma_f16(const __half* __restrict__ A,
    const float* __restrict__ B, __half* __restrict__ C, int M) {
  __shared__ char smem[SMEM_BYTES];
  gemm_body<true>(A, B, C, M, blockIdx.x * 128, smem);
}

// ============ fused A: binsort1 || gemm1 (first G1a tiles) || pack_heads_w ============
// binsort1 is LDS-atomic/latency-bound (low VALU, low BW); the MFMA gemm is
// compute-dense. Co-residency overlaps the independent gemm1 under the CSR build.
__global__ __launch_bounds__(256) void fusedA(const int* __restrict__ src,
    const int* __restrict__ dst, int* __restrict__ tmp, int* __restrict__ bofs,
    int* __restrict__ bintot, int NBC, int E, int nblk,
    const float* __restrict__ x, const float* __restrict__ W1,
    __half* __restrict__ h16, int N, int G1a,
    const float* __restrict__ piW, const float* __restrict__ muW,
    const float* __restrict__ lsW, float* __restrict__ W64) {
  __shared__ char smem[SMEM_BYTES];
  int b = blockIdx.x;
  if (b < nblk) {
    binsort1_body(src, dst, tmp, bofs, bintot, NBC, E, b, smem);
  } else if (b < nblk + G1a) {
    gemm_body<false>(x, W1, h16, N, (b - nblk) * 128, smem);
  } else {
    int i = (b - nblk - G1a) * 256 + threadIdx.x;
    if (i < 128 * 64) {
      int k = i >> 6, j = i & 63;
      float v = 0.f;
      if (j < 20)      v = piW[k * 20 + j];
      else if (j < 40) v = muW[k * 20 + (j - 20)];
      else if (j < 60) v = lsW[k * 20 + (j - 40)];
      W64[i] = v;
    }
  }
}

// ============ fused B: binsort2 || gemm1 (remaining tiles) ============
__global__ __launch_bounds__(256) void fusedB(const int* __restrict__ tmp,
    const int* __restrict__ bofs, const int* __restrict__ binbase,
    int* __restrict__ csrc, int* __restrict__ cnt, float* __restrict__ dis,
    int* __restrict__ offs, int NBC, int nblk, int N,
    const float* __restrict__ x, const float* __restrict__ W1,
    __half* __restrict__ h16, int G1a) {
  __shared__ char smem[SMEM_BYTES];
  int b = blockIdx.x;
  if (b < NBC) {
    binsort2_body(tmp, bofs, binbase, csrc, cnt, dis, offs, NBC, nblk, N, b, smem);
  } else {
    gemm_body<false>(x, W1, h16, N, (G1a + b - NBC) * 128, smem);
  }
}

// ============ scan bin totals -> bin bases (1 block) ============
__global__ __launch_bounds__(512) void binscan(const int* __restrict__ bintot,
                                               int* __restrict__ binbase, int NBC) {
  __shared__ int s[512];
  int tid = threadIdx.x;
  int v = (tid < NBC) ? bintot[tid] : 0;
  s[tid] = v;
  __syncthreads();
  for (int o = 1; o < 512; o <<= 1) {
    int t = (tid >= o) ? s[tid - o] : 0;
    __syncthreads();
    s[tid] += t;
    __syncthreads();
  }
  if (tid < NBC) binbase[tid] = s[tid] - v;
}

// ============ aggregation: two nodes per wave, interleaved gather chains ============
// PROVEN (115 us @ 3.75 TB/s pattern roofline -- 3 falsifications: 2x concurrency
// flat (R2), barrier-phasing -2.2x (R3), channel-chunking -3.2x (R5)). OutT=__half
// for layer 1 (rounding point identical; write traffic halves).
template<typename OutT>
__global__ __launch_bounds__(256) void agg_kernel(const __half* __restrict__ h,
    const int* __restrict__ csrc,
    const int* __restrict__ offs, const int* __restrict__ cnt,
    const float* __restrict__ dis, const float* __restrict__ bias,
    OutT* __restrict__ out, int n) {
  int wave = threadIdx.x >> 6;
  int lane = threadIdx.x & 63;
  int i0 = (blockIdx.x * 4 + wave) * 2;
  if (i0 >= n) return;
  int i1 = i0 + 1;
  bool has1 = i1 < n;
  int c = lane * 2;

  int st0 = offs[i0];
  int m0  = cnt[i0];
  float d0 = dis[i0];
  int st1 = 0, m1 = 0;
  float d1 = 0.f;
  if (has1) { st1 = offs[i1]; m1 = cnt[i1]; d1 = dis[i1]; }

  float ax0 = 0.f, ay0 = 0.f, ax1 = 0.f, ay1 = 0.f;
  int mMax = m0 > m1 ? m0 : m1;

  for (int base = 0; base < mMax; base += 64) {
    int mcA = m0 - base; mcA = mcA < 0 ? 0 : (mcA > 64 ? 64 : mcA);
    int mcB = m1 - base; mcB = mcB < 0 ? 0 : (mcB > 64 ? 64 : mcB);
    int mc = mcA > mcB ? mcA : mcB;

    int sA = 0, sB = 0;
    float wA = 0.f, wB = 0.f;
    if (lane < mcA) sA = csrc[st0 + base + lane];
    if (lane < mcB) sB = csrc[st1 + base + lane];
    if (lane < mcA) wA = dis[sA] * d0;
    if (lane < mcB) wB = dis[sB] * d1;

    int j = 0;
    for (; j + 4 <= mc; j += 4) {
      int   a0 = __shfl(sA, j);
      int   a1 = __shfl(sA, j + 1);
      int   a2 = __shfl(sA, j + 2);
      int   a3 = __shfl(sA, j + 3);
      int   b0 = __shfl(sB, j);
      int   b1 = __shfl(sB, j + 1);
      int   b2 = __shfl(sB, j + 2);
      int   b3 = __shfl(sB, j + 3);
      float u0 = __shfl(wA, j);
      float u1 = __shfl(wA, j + 1);
      float u2 = __shfl(wA, j + 2);
      float u3 = __shfl(wA, j + 3);
      float v0 = __shfl(wB, j);
      float v1 = __shfl(wB, j + 1);
      float v2 = __shfl(wB, j + 2);
      float v3 = __shfl(wB, j + 3);
      float2 hA0 = __half22float2(*(const __half2*)(h + ((size_t)a0 << 7) + c));
      float2 hA1 = __half22float2(*(const __half2*)(h + ((size_t)a1 << 7) + c));
      float2 hA2 = __half22float2(*(const __half2*)(h + ((size_t)a2 << 7) + c));
      float2 hA3 = __half22float2(*(const __half2*)(h + ((size_t)a3 << 7) + c));
      float2 hB0 = __half22float2(*(const __half2*)(h + ((size_t)b0 << 7) + c));
      float2 hB1 = __half22float2(*(const __half2*)(h + ((size_t)b1 << 7) + c));
      float2 hB2 = __half22float2(*(const __half2*)(h + ((size_t)b2 << 7) + c));
      float2 hB3 = __half22float2(*(const __half2*)(h + ((size_t)b3 << 7) + c));
      ax0 = fmaf(hA0.x, u0, ax0); ay0 = fmaf(hA0.y, u0, ay0);
      ax0 = fmaf(hA1.x, u1, ax0); ay0 = fmaf(hA1.y, u1, ay0);
      ax0 = fmaf(hA2.x, u2, ax0); ay0 = fmaf(hA2.y, u2, ay0);
      ax0 = fmaf(hA3.x, u3, ax0); ay0 = fmaf(hA3.y, u3, ay0);
      ax1 = fmaf(hB0.x, v0, ax1); ay1 = fmaf(hB0.y, v0, ay1);
      ax1 = fmaf(hB1.x, v1, ax1); ay1 = fmaf(hB1.y, v1, ay1);
      ax1 = fmaf(hB2.x, v2, ax1); ay1 = fmaf(hB2.y, v2, ay1);
      ax1 = fmaf(hB3.x, v3, ax1); ay1 = fmaf(hB3.y, v3, ay1);
    }
    for (; j < mc; ++j) {
      int   a0 = __shfl(sA, j);
      int   b0 = __shfl(sB, j);
      float u0 = __shfl(wA, j);
      float v0 = __shfl(wB, j);
      float2 hA0 = __half22float2(*(const __half2*)(h + ((size_t)a0 << 7) + c));
      float2 hB0 = __half22float2(*(const __half2*)(h + ((size_t)b0 << 7) + c));
      ax0 = fmaf(hA0.x, u0, ax0); ay0 = fmaf(hA0.y, u0, ay0);
      ax1 = fmaf(hB0.x, v0, ax1); ay1 = fmaf(hB0.y, v0, ay1);
    }
  }

  float2 bv = *(const float2*)(bias + c);
  {
    float dd = d0 * d0;
    float2 hs = __half22float2(*(const __half2*)(h + ((size_t)i0 << 7) + c));
    float vx = fmaxf(fmaf(hs.x, dd, ax0) + bv.x, 0.f);
    float vy = fmaxf(fmaf(hs.y, dd, ay0) + bv.y, 0.f);
    if constexpr (sizeof(OutT) == 2) {
      *(__half2*)((__half*)out + (size_t)i0 * 128 + c) = __floats2half2_rn(vx, vy);
    } else {
      *(float2*)((float*)out + (size_t)i0 * 128 + c) = make_float2(vx, vy);
    }
  }
  if (has1) {
    float dd = d1 * d1;
    float2 hs = __half22float2(*(const __half2*)(h + ((size_t)i1 << 7) + c));
    float vx = fmaxf(fmaf(hs.x, dd, ax1) + bv.x, 0.f);
    float vy = fmaxf(fmaf(hs.y, dd, ay1) + bv.y, 0.f);
    if constexpr (sizeof(OutT) == 2) {
      *(__half2*)((__half*)out + (size_t)i1 * 128 + c) = __floats2half2_rn(vx, vy);
    } else {
      *(float2*)((float*)out + (size_t)i1 * 128 + c) = make_float2(vx, vy);
    }
  }
}

// ============ fused heads: GEMM [M,128]@[128,64] + bias + softmax(20) + scatter ====
#define KC 64
__global__ __launch_bounds__(256) void heads_fused(const float* __restrict__ A,
    const float* __restrict__ B, const float* __restrict__ pib,
    const float* __restrict__ mub, const float* __restrict__ lsb,
    float* __restrict__ out, int n) {
  __shared__ float sA[64][KC + 4];
  __shared__ float sB[KC][68];
  __shared__ float sOut[64][68];
  int tid = threadIdx.x;
  int m0 = blockIdx.x * 64;
  int tr = tid >> 4;   // 0..15
  int tc = tid & 15;   // 0..15
  float acc[4][4];
#pragma unroll
  for (int i = 0; i < 4; ++i)
#pragma unroll
    for (int j = 0; j < 4; ++j) acc[i][j] = 0.f;

  for (int k0 = 0; k0 < 128; k0 += KC) {
#pragma unroll
    for (int q = 0; q < 4; ++q) {
      int idx = q * 256 + tid;
      int r = idx >> 4;
      int kk = (idx & 15) << 2;
      float4 v = make_float4(0.f, 0.f, 0.f, 0.f);
      if (m0 + r < n) v = *(const float4*)(A + (size_t)(m0 + r) * 128 + k0 + kk);
      *(float4*)(&sA[r][kk]) = v;
    }
#pragma unroll
    for (int q = 0; q < 4; ++q) {
      int idx = q * 256 + tid;
      int kk = idx >> 4;
      int nn = (idx & 15) << 2;
      *(float4*)(&sB[kk][nn]) = *(const float4*)(B + (size_t)(k0 + kk) * 64 + nn);
    }
    __syncthreads();
#pragma unroll 4
    for (int k = 0; k < KC; k += 4) {
      float4 a0 = *(const float4*)(&sA[tr][k]);
      float4 a1 = *(const float4*)(&sA[tr + 16][k]);
      float4 a2 = *(const float4*)(&sA[tr + 32][k]);
      float4 a3 = *(const float4*)(&sA[tr + 48][k]);
#pragma unroll
      for (int u = 0; u < 4; ++u) {
        float4 b = *(const float4*)(&sB[k + u][tc * 4]);
        float av[4] = {((const float*)&a0)[u], ((const float*)&a1)[u],
                       ((const float*)&a2)[u], ((const float*)&a3)[u]};
#pragma unroll
        for (int i = 0; i < 4; ++i) {
          acc[i][0] = fmaf(av[i], b.x, acc[i][0]);
          acc[i][1] = fmaf(av[i], b.y, acc[i][1]);
          acc[i][2] = fmaf(av[i], b.z, acc[i][2]);
          acc[i][3] = fmaf(av[i], b.w, acc[i][3]);
        }
      }
    }
    __syncthreads();
  }

#pragma unroll
  for (int i = 0; i < 4; ++i)
#pragma unroll
    for (int j = 0; j < 4; ++j) sOut[tr + 16 * i][tc * 4 + j] = acc[i][j];
  __syncthreads();

  int wave = tid >> 6, lane = tid & 63;
  size_t nb = (size_t)n * NG;
  for (int t = 0; t < 16; ++t) {
    int rr = wave * 16 + t;
    int node = m0 + rr;
    if (node >= n) break;   // wave-uniform
    float v = 0.f;
    if (lane < 60) {
      v = sOut[rr][lane];
      v += (lane < 20) ? pib[lane] : (lane < 40) ? mub[lane - 20] : lsb[lane - 40];
    }
    float pv = (lane < 20) ? v : -__builtin_inff();
    float mx = pv;
    for (int o = 16; o > 0; o >>= 1) mx = fmaxf(mx, __shfl_down(mx, o, 32));
    mx = __shfl(mx, 0, 32);
    float ev = (lane < 20) ? expf(v - mx) : 0.f;
    float sm = ev;
    for (int o = 16; o > 0; o >>= 1) sm += __shfl_down(sm, o, 32);
    sm = __shfl(sm, 0, 32);
    if (lane < 20)      out[(size_t)node * NG + lane] = ev / sm;
    else if (lane < 40) out[nb + (size_t)node * NG + (lane - 20)] = v;
    else if (lane < 60) out[2 * nb + (size_t)node * NG + (lane - 40)] = v;
  }
}

extern "C" void kernel_launch(void* const* d_in, const int* in_sizes, int n_in,
                              void* d_out, int out_size, void* d_ws, size_t ws_size,
                              hipStream_t stream) {
  const float* x   = (const float*)d_in[0];
  const int*   ei  = (const int*)d_in[1];
  const float* W1  = (const float*)d_in[2];
  const float* b1  = (const float*)d_in[3];
  const float* W2  = (const float*)d_in[4];
  const float* b2  = (const float*)d_in[5];
  const float* piW = (const float*)d_in[6];
  const float* pib = (const float*)d_in[7];
  const float* muW = (const float*)d_in[8];
  const float* mub = (const float*)d_in[9];
  const float* lsW = (const float*)d_in[10];
  const float* lsb = (const float*)d_in[11];
  float* out = (float*)d_out;

  const int N = in_sizes[0] / IN_DIM;
  const int E = in_sizes[1] / 2;
  const int* src = ei;
  const int* dst = ei + E;

  const int NBC  = (N + 255) >> 8;          // 391 coarse bins
  const int nblk = (E + T - 1) / T;         // 782 level-1 blocks
  const int ST   = NBC + 1;

  // workspace layout
  char* p = (char*)d_ws;
  char* regionH = p;                        p += (size_t)N * HID * sizeof(__half);
  __half* h16  = (__half*)regionH;
  char* regionR = p;                        // tmp -> bufB16 -> bufB (sequential reuse)
  size_t szR = (size_t)N * HID * sizeof(float);
  size_t szT = (size_t)E * sizeof(int);
  p += (szR > szT ? szR : szT);
  int*    tmp    = (int*)regionR;
  __half* bufB16 = (__half*)regionR;
  float*  bufB   = (float*)regionR;
  int*   csrc   = (int*)p;                  p += (size_t)E * sizeof(int);
  int*   bofs   = (int*)p;                  p += (size_t)nblk * ST * sizeof(int);
  int*   bintot = (int*)p;                  p += (size_t)MAXB * sizeof(int);
  int*   binbase= (int*)p;                  p += (size_t)MAXB * sizeof(int);
  int*   cnt    = (int*)p;                  p += (size_t)N * sizeof(int);
  int*   offs   = (int*)p;                  p += (size_t)N * sizeof(int);
  float* dis    = (float*)p;                p += (size_t)N * sizeof(float);
  float* W64    = (float*)p;                p += (size_t)128 * 64 * sizeof(float);

  const int NB8 = (N + 7) / 8;          // agg: 2 nodes/wave, 4 waves/block
  const int NBG = (N + 127) / 128;      // mfma gemm tiles
  const int G1a = (NBG + 1) / 2;        // gemm1 tiles overlapped with binsort1
  const int G1b = NBG - G1a;            // gemm1 tiles overlapped with binsort2
  const int PACKB = (128 * 64 + 255) / 256;

  // ---- CSR build overlapped with gemm1 (independent workloads) ----
  zero_ints<<<(NBC + 255) / 256, 256, 0, stream>>>(bintot, NBC);
  fusedA<<<nblk + G1a + PACKB, 256, 0, stream>>>(src, dst, tmp, bofs, bintot,
      NBC, E, nblk, x, W1, h16, N, G1a, piW, muW, lsW, W64);
  binscan<<<1, 512, 0, stream>>>(bintot, binbase, NBC);
  fusedB<<<NBC + G1b, 256, 0, stream>>>(tmp, bofs, binbase, csrc, cnt, dis, offs,
      NBC, nblk, N, x, W1, h16, G1a);

  // ---- serial chain ----
  agg_kernel<__half><<<NB8, 256, 0, stream>>>(h16, csrc, offs, cnt, dis, b1,
                                              bufB16, N);
  gemm128_mfma_f16<<<NBG, 256, 0, stream>>>(bufB16, W2, h16, N);
  agg_kernel<float><<<NB8, 256, 0, stream>>>(h16, csrc, offs, cnt, dis, b2,
                                             bufB, N);
  heads_fused<<<(N + 63) / 64, 256, 0, stream>>>(bufB, W64, pib, mub, lsb, out, N);
}